// Round 6
// baseline (1439.631 us; speedup 1.0000x reference)
//
#include <hip/hip_runtime.h>
#include <hip/hip_bf16.h>

// ---------------------------------------------------------------------------
// VIN forward, fp32 (r6 == r5 + spill fix).
// r4 measured: 1047 us; conv3 ~500 us @ 25% occ, conv2 ~450 us;
// latency-bound: VALUBusy 63%, HBM 3.6%, MfmaUtil 0.
//   - conv_bn_pool: software-pipelined staging — prefetch next ci-chunk's
//     global loads into registers (raw) before the FMA phase; bn+relu+pad
//     applied at ds_write time next iteration. Loads overlap compute.
//   - conv2 CO_T=8 (was 16: acc64+st19 ~130 VGPR would spill at the 128 cap),
//     conv3 CO_T=4. Re-read traffic is irrelevant at 3.6% HBM.
//   - __launch_bounds__(256,4) caps VGPR at 128 for 4 blocks/CU.
// ---------------------------------------------------------------------------

// ---------------- conv1: X(32,3,128,128) -> pool1(32,64,64,64) -------------
__global__ __launch_bounds__(256)
void conv1_pool_kernel(const float* __restrict__ X, const float* __restrict__ W,
                       const float* __restrict__ Bias, float* __restrict__ out)
{
    const int sp  = blockIdx.x;          // 16 spatial tiles (4x4 of 16x16 pooled)
    const int n   = blockIdx.y;
    const int ty0 = (sp >> 2) * 16;      // pooled row origin
    const int tx0 = (sp & 3) * 16;
    const int tid = threadIdx.x;
    const int px = tid & 15, py = tid >> 4;

    __shared__ float s_in[3][34][34];    // shifted: s_in[ci][cy+dy][cx+dx]

    const int gy0 = 2 * ty0 - 1, gx0 = 2 * tx0 - 1;
    for (int idx = tid; idx < 3 * 1156; idx += 256) {
        int ci = idx / 1156, rem = idx - ci * 1156;
        int ly = rem / 34, lx = rem - ly * 34;
        int gy = gy0 + ly, gx = gx0 + lx;
        float v = 0.f;
        if ((unsigned)gy < 128u && (unsigned)gx < 128u)
            v = X[((n * 3 + ci) << 14) + (gy << 7) + gx];
        s_in[ci][ly][lx] = v;
    }
    __syncthreads();

    float patch[3][4][4];
    #pragma unroll
    for (int ci = 0; ci < 3; ++ci)
        #pragma unroll
        for (int r = 0; r < 4; ++r) {
            float2 a = *(const float2*)&s_in[ci][2 * py + r][2 * px];
            float2 b = *(const float2*)&s_in[ci][2 * py + r][2 * px + 2];
            patch[ci][r][0] = a.x; patch[ci][r][1] = a.y;
            patch[ci][r][2] = b.x; patch[ci][r][3] = b.y;
        }

    const int out_base = ((n * 64) << 12) + (ty0 + py) * 64 + tx0 + px;
    #pragma unroll 1
    for (int co = 0; co < 64; ++co) {
        float wk[27];                    // wave-uniform -> s_load
        const float* wp = W + co * 27;
        #pragma unroll
        for (int k = 0; k < 27; ++k) wk[k] = wp[k];
        float b0 = Bias[co];
        float a0 = b0, a1 = b0, a2 = b0, a3 = b0;
        #pragma unroll
        for (int ci = 0; ci < 3; ++ci)
            #pragma unroll
            for (int dy = 0; dy < 3; ++dy)
                #pragma unroll
                for (int dx = 0; dx < 3; ++dx) {
                    float w = wk[ci * 9 + dy * 3 + dx];
                    a0 = fmaf(w, patch[ci][dy][dx],     a0);
                    a1 = fmaf(w, patch[ci][dy][dx + 1], a1);
                    a2 = fmaf(w, patch[ci][dy + 1][dx], a2);
                    a3 = fmaf(w, patch[ci][dy + 1][dx + 1], a3);
                }
        out[out_base + (co << 12)] = fmaxf(fmaxf(a0, a1), fmaxf(a2, a3));
    }
}

// ---------------- BN stats: pooled (32,C,HW) -> a[c], c[c] -----------------
__global__ __launch_bounds__(1024)
void bn_stats_kernel(const float* __restrict__ data, const float* __restrict__ g,
                     const float* __restrict__ b, float* __restrict__ a_out,
                     float* __restrict__ c_out, int C, int HW)
{
    const int c = blockIdx.x;
    const int tid = threadIdx.x;
    const int nthr = blockDim.x;
    float s = 0.f, s2 = 0.f;
    for (int n = 0; n < 32; ++n) {
        const float* p = data + (size_t)(n * C + c) * HW;
        for (int i = tid * 4; i < HW; i += 4 * nthr) {
            float4 v = *(const float4*)(p + i);
            s  += v.x + v.y + v.z + v.w;
            s2 += v.x * v.x + v.y * v.y + v.z * v.z + v.w * v.w;
        }
    }
    __shared__ float rs[1024], rs2[1024];
    rs[tid] = s; rs2[tid] = s2;
    __syncthreads();
    for (int off = nthr >> 1; off > 0; off >>= 1) {
        if (tid < off) { rs[tid] += rs[tid + off]; rs2[tid] += rs2[tid + off]; }
        __syncthreads();
    }
    if (tid == 0) {
        float cnt = 32.f * (float)HW;
        float mean = rs[0] / cnt;
        float var  = rs2[0] / cnt - mean * mean;
        float a = g[c] * rsqrtf(var + 1e-5f);
        a_out[c] = a;
        c_out[c] = b[c] - mean * a;
    }
}

// ------ conv(CIN->128, 3x3 pad1) on bn-relu'd input + maxpool2 -------------
// Software-pipelined: chunk k+1's global loads issue before chunk k's FMAs.
template <int CIN, int WIN, int CO_T>
__global__ __launch_bounds__(256, 4)
void conv_bn_pool_kernel(const float* __restrict__ in, const float* __restrict__ W,
                         const float* __restrict__ Bias, const float* __restrict__ bn_a,
                         const float* __restrict__ bn_c, float* __restrict__ out)
{
    constexpr int WOUT  = WIN / 2;
    constexpr int SPT   = WOUT / 16;
    constexpr int CI_T  = 4;
    constexpr int NELEM = CI_T * 34 * 34;            // 4624
    constexpr int NITER = (NELEM + 255) / 256;       // 19
    const int cot = blockIdx.x;
    const int sp  = blockIdx.y;
    const int n   = blockIdx.z;
    const int ty0 = (sp / SPT) * 16, tx0 = (sp % SPT) * 16;
    const int tid = threadIdx.x;
    const int px = tid & 15, py = tid >> 4;

    __shared__ float s_in[CI_T][34][34];

    float acc[CO_T][4];
    #pragma unroll
    for (int co = 0; co < CO_T; ++co) {
        float b0 = Bias[cot * CO_T + co];
        acc[co][0] = b0; acc[co][1] = b0; acc[co][2] = b0; acc[co][3] = b0;
    }

    const int gy0 = 2 * ty0 - 1, gx0 = 2 * tx0 - 1;
    const float* Wbase = W + (size_t)(cot * CO_T) * CIN * 9;

    float st[NITER];                   // raw prefetched values (static idx only)
    unsigned inb_mask;                 // bit k: element k is in-bounds

    // issue global loads for chunk at ci0 (NO dependent math -> no vm wait here)
    auto issue_loads = [&](int ci0) {
        inb_mask = 0u;
        #pragma unroll
        for (int k = 0; k < NITER; ++k) {
            int idx = tid + 256 * k;
            int ci  = idx / 1156;
            int rem = idx - ci * 1156;
            int ly  = rem / 34, lx = rem - ly * 34;
            int gy  = gy0 + ly, gx = gx0 + lx;
            bool inb = (idx < NELEM) && ((unsigned)gy < (unsigned)WIN)
                                     && ((unsigned)gx < (unsigned)WIN);
            float v = 0.f;
            if (inb)
                v = in[(size_t)(n * CIN + ci0 + ci) * (WIN * WIN) + gy * WIN + gx];
            st[k] = v;
            inb_mask |= (unsigned)inb << k;
        }
    };

    issue_loads(0);

    #pragma unroll 1
    for (int ci0 = 0; ci0 < CIN; ci0 += CI_T) {
        __syncthreads();               // previous chunk's readers done
        // write prefetched chunk to LDS, applying bn+relu (pad stays 0)
        float* sflat = &s_in[0][0][0];
        #pragma unroll
        for (int k = 0; k < NITER; ++k) {
            int idx = tid + 256 * k;
            if (idx < NELEM) {
                int ci = idx / 1156;
                float a = bn_a[ci0 + ci], c = bn_c[ci0 + ci];
                float w = fmaxf(fmaf(st[k], a, c), 0.f);
                sflat[idx] = ((inb_mask >> k) & 1u) ? w : 0.f;
            }
        }
        __syncthreads();               // LDS ready
        if (ci0 + CI_T < CIN) issue_loads(ci0 + CI_T);   // overlap with FMAs

        #pragma unroll
        for (int ci = 0; ci < CI_T; ++ci) {
            float patch[4][4];
            #pragma unroll
            for (int r = 0; r < 4; ++r) {
                float2 a = *(const float2*)&s_in[ci][2 * py + r][2 * px];
                float2 b = *(const float2*)&s_in[ci][2 * py + r][2 * px + 2];
                patch[r][0] = a.x; patch[r][1] = a.y;
                patch[r][2] = b.x; patch[r][3] = b.y;
            }
            const float* wp = Wbase + (size_t)(ci0 + ci) * 9;
            #pragma unroll
            for (int co = 0; co < CO_T; ++co) {
                float wk[9];           // wave-uniform -> s_load
                #pragma unroll
                for (int k = 0; k < 9; ++k) wk[k] = wp[(size_t)co * CIN * 9 + k];
                #pragma unroll
                for (int dy = 0; dy < 3; ++dy)
                    #pragma unroll
                    for (int dx = 0; dx < 3; ++dx) {
                        float w = wk[dy * 3 + dx];
                        acc[co][0] = fmaf(w, patch[dy][dx],         acc[co][0]);
                        acc[co][1] = fmaf(w, patch[dy][dx + 1],     acc[co][1]);
                        acc[co][2] = fmaf(w, patch[dy + 1][dx],     acc[co][2]);
                        acc[co][3] = fmaf(w, patch[dy + 1][dx + 1], acc[co][3]);
                    }
            }
        }
    }

    const size_t out_base = (size_t)(n * 128 + cot * CO_T) * (WOUT * WOUT)
                          + (ty0 + py) * WOUT + tx0 + px;
    #pragma unroll
    for (int co = 0; co < CO_T; ++co) {
        float m = fmaxf(fmaxf(acc[co][0], acc[co][1]), fmaxf(acc[co][2], acc[co][3]));
        out[out_base + (size_t)co * (WOUT * WOUT)] = m;
    }
}

// ---------------- VIN head: one block per image ----------------------------
__global__ __launch_bounds__(256)
void vin_kernel(const float* __restrict__ pool3, const float* __restrict__ bn_a,
                const float* __restrict__ bn_c, const float* __restrict__ r_w,
                const float* __restrict__ q_w, const float* __restrict__ w_vi,
                const float* __restrict__ crit_w, const float* __restrict__ crit_b,
                const int* __restrict__ Kp, float* __restrict__ out_critic,
                float* __restrict__ out_q)
{
    const int n = blockIdx.x;
    const int tid = threadIdx.x;           // 256 = 16x16 positions
    const int px = tid & 15, py = tid >> 4;

    __shared__ float s_cr[16][256];        // conv_r[co][pos]
    __shared__ float s_v[20][20];          // padded plane (r, then v)
    __shared__ float s_qw[16][25];
    __shared__ float s_wvi[16][25];
    __shared__ float s_rw[128];
    __shared__ float s_red[256];

    for (int i = tid; i < 400; i += 256) {
        s_qw[i / 25][i % 25]  = q_w[i];
        s_wvi[i / 25][i % 25] = w_vi[i];
        s_v[i / 20][i % 20]   = 0.f;
    }
    if (tid < 128) s_rw[tid] = r_w[tid];
    __syncthreads();

    // r[pos] = sum_ci relu(bn3(pool3)) * r_w[ci]
    float r = 0.f;
    const float* p3 = pool3 + (size_t)n * 128 * 256 + tid;
    #pragma unroll 4
    for (int ci = 0; ci < 128; ++ci) {
        float x = p3[ci * 256];
        x = fmaxf(fmaf(x, bn_a[ci], bn_c[ci]), 0.f);
        r = fmaf(x, s_rw[ci], r);
    }
    s_v[py + 2][px + 2] = r;               // padded r plane
    __syncthreads();

    // conv_r = conv5x5(r, q_w), initial v = max_co conv_r
    float cr[16];
    #pragma unroll
    for (int co = 0; co < 16; ++co) cr[co] = 0.f;
    #pragma unroll
    for (int dy = 0; dy < 5; ++dy)
        #pragma unroll
        for (int dx = 0; dx < 5; ++dx) {
            float rv = s_v[py + dy][px + dx];
            #pragma unroll
            for (int co = 0; co < 16; ++co)
                cr[co] = fmaf(s_qw[co][dy * 5 + dx], rv, cr[co]);
        }
    float v = cr[0];
    #pragma unroll
    for (int co = 0; co < 16; ++co) { s_cr[co][tid] = cr[co]; v = fmaxf(v, cr[co]); }
    __syncthreads();                       // all reads of r plane done
    s_v[py + 2][px + 2] = v;
    __syncthreads();

    const int K = Kp[0];
    float q[16];
    #pragma unroll 1
    for (int it = 0; it < K; ++it) {
        #pragma unroll
        for (int co = 0; co < 16; ++co) q[co] = s_cr[co][tid];
        #pragma unroll
        for (int dy = 0; dy < 5; ++dy)
            #pragma unroll
            for (int dx = 0; dx < 5; ++dx) {
                float vv = s_v[py + dy][px + dx];
                #pragma unroll
                for (int co = 0; co < 16; ++co)
                    q[co] = fmaf(s_wvi[co][dy * 5 + dx], vv, q[co]);
            }
        float nv = q[0];
        #pragma unroll
        for (int co = 1; co < 16; ++co) nv = fmaxf(nv, q[co]);
        __syncthreads();                   // all reads of old v done
        s_v[py + 2][px + 2] = nv;
        __syncthreads();                   // new v visible
        v = nv;
    }

    // q output: (B, 16, 16, 16) -> flat 4096 per image
    #pragma unroll
    for (int co = 0; co < 16; ++co)
        out_q[(size_t)n * 4096 + co * 256 + tid] = q[co];

    // critic[n] = sum_pos v*crit_w + crit_b
    s_red[tid] = v * crit_w[tid];
    __syncthreads();
    for (int off = 128; off > 0; off >>= 1) {
        if (tid < off) s_red[tid] += s_red[tid + off];
        __syncthreads();
    }
    if (tid == 0) out_critic[n] = s_red[0] + crit_b[0];
}

// ---------------------------------------------------------------------------
extern "C" void kernel_launch(void* const* d_in, const int* in_sizes, int n_in,
                              void* d_out, int out_size, void* d_ws, size_t ws_size,
                              hipStream_t stream)
{
    const float* X      = (const float*)d_in[0];
    // d_in[1] = obs (unused)
    const float* h1_w   = (const float*)d_in[2];
    const float* h1_b   = (const float*)d_in[3];
    const float* bn1_g  = (const float*)d_in[4];
    const float* bn1_b  = (const float*)d_in[5];
    const float* h2_w   = (const float*)d_in[6];
    const float* h2_b   = (const float*)d_in[7];
    const float* bn2_g  = (const float*)d_in[8];
    const float* bn2_b  = (const float*)d_in[9];
    const float* h3_w   = (const float*)d_in[10];
    const float* h3_b   = (const float*)d_in[11];
    const float* bn3_g  = (const float*)d_in[12];
    const float* bn3_b  = (const float*)d_in[13];
    const float* r_w    = (const float*)d_in[14];
    const float* q_w    = (const float*)d_in[15];
    const float* w_vi   = (const float*)d_in[16];
    const float* crit_w = (const float*)d_in[17];
    const float* crit_b = (const float*)d_in[18];
    const int*   Kp     = (const int*)d_in[19];

    float* ws    = (float*)d_ws;
    float* pool1 = ws;                         // 32*64*64*64   = 8388608
    float* pool2 = pool1 + 8388608;            // 32*128*32*32  = 4194304
    float* pool3 = pool2 + 4194304;            // 32*128*16*16  = 1048576
    float* bn1a  = pool3 + 1048576;
    float* bn1c  = bn1a + 64;
    float* bn2a  = bn1c + 64;
    float* bn2c  = bn2a + 128;
    float* bn3a  = bn2c + 128;
    float* bn3c  = bn3a + 128;

    float* out_critic = (float*)d_out;         // 32
    float* out_q      = out_critic + 32;       // 32*4096

    conv1_pool_kernel<<<dim3(16, 32), 256, 0, stream>>>(X, h1_w, h1_b, pool1);
    bn_stats_kernel<<<64, 1024, 0, stream>>>(pool1, bn1_g, bn1_b, bn1a, bn1c, 64, 4096);
    conv_bn_pool_kernel<64, 64, 8><<<dim3(16, 4, 32), 256, 0, stream>>>(
        pool1, h2_w, h2_b, bn1a, bn1c, pool2);
    bn_stats_kernel<<<128, 1024, 0, stream>>>(pool2, bn2_g, bn2_b, bn2a, bn2c, 128, 1024);
    conv_bn_pool_kernel<128, 32, 4><<<dim3(32, 1, 32), 256, 0, stream>>>(
        pool2, h3_w, h3_b, bn2a, bn2c, pool3);
    bn_stats_kernel<<<128, 1024, 0, stream>>>(pool3, bn3_g, bn3_b, bn3a, bn3c, 128, 256);
    vin_kernel<<<32, 256, 0, stream>>>(pool3, bn3a, bn3c, r_w, q_w, w_vi,
                                       crit_w, crit_b, Kp, out_critic, out_q);
}

// Round 9
// 825.115 us; speedup vs baseline: 1.7448x; 1.7448x over previous
//
#include <hip/hip_runtime.h>
#include <hip/hip_bf16.h>

// ---------------------------------------------------------------------------
// VIN forward, fp32 (r9 == r8 + 16B-aligned LDS staging buffers).
// Measured: r4 = 1047 us (convs ~500 us, latency-bound: VALU 63%, 25% occ,
//           HBM 3.6%). r6 = 1440 us (reg-prefetch spilled: FETCH 935 MB).
// r9: async global_load_lds (width 16) + double-buffered LDS, one barrier per
//     ci-chunk (issue next DMA -> compute current -> barrier drains).
//     conv1 writes RAW conv+bias directly into a zero-memset PADDED buffer
//     (66 rows x 68-wide, 16B-aligned rows); bn1 stats read the full padded
//     plane (zeros don't perturb sums; count corrected); bn1 applied IN-PLACE.
//     bn2 materializes a padded 34x34 activation (linear DMA for conv3).
//     High-water ws = 53.5 MB (r4 proved >= 54.5 MB available).
//     conv2 CO_T=16, conv3 CO_T=4 (both 4 blocks/CU).
//     Staging guard keeps active lanes a PREFIX of each wave (global_load_lds
//     writes M0(first active lane) + lane*16 -> prefix-active is safe).
// ---------------------------------------------------------------------------

// ------- conv1: X(32,3,128,128) -> padded1(32,64,66,68) raw conv+bias ------
__global__ __launch_bounds__(256)
void conv1_pool_kernel(const float* __restrict__ X, const float* __restrict__ W,
                       const float* __restrict__ Bias, float* __restrict__ out)
{
    const int sp  = blockIdx.x;          // 16 spatial tiles (4x4 of 16x16 pooled)
    const int n   = blockIdx.y;
    const int ty0 = (sp >> 2) * 16;      // pooled row origin
    const int tx0 = (sp & 3) * 16;
    const int tid = threadIdx.x;
    const int px = tid & 15, py = tid >> 4;

    __shared__ float s_in[3][34][34];    // shifted: s_in[ci][cy+dy][cx+dx]

    const int gy0 = 2 * ty0 - 1, gx0 = 2 * tx0 - 1;
    for (int idx = tid; idx < 3 * 1156; idx += 256) {
        int ci = idx / 1156, rem = idx - ci * 1156;
        int ly = rem / 34, lx = rem - ly * 34;
        int gy = gy0 + ly, gx = gx0 + lx;
        float v = 0.f;
        if ((unsigned)gy < 128u && (unsigned)gx < 128u)
            v = X[((n * 3 + ci) << 14) + (gy << 7) + gx];
        s_in[ci][ly][lx] = v;
    }
    __syncthreads();

    float patch[3][4][4];
    #pragma unroll
    for (int ci = 0; ci < 3; ++ci)
        #pragma unroll
        for (int r = 0; r < 4; ++r) {
            float2 a = *(const float2*)&s_in[ci][2 * py + r][2 * px];
            float2 b = *(const float2*)&s_in[ci][2 * py + r][2 * px + 2];
            patch[ci][r][0] = a.x; patch[ci][r][1] = a.y;
            patch[ci][r][2] = b.x; patch[ci][r][3] = b.y;
        }

    // padded1 plane: 66 rows x 68 cols; inner at [1..64][1..64]
    const size_t out_base = (size_t)n * 64 * 4488
                          + (size_t)(ty0 + py + 1) * 68 + (tx0 + px + 1);
    #pragma unroll 1
    for (int co = 0; co < 64; ++co) {
        float wk[27];                    // wave-uniform -> s_load
        const float* wp = W + co * 27;
        #pragma unroll
        for (int k = 0; k < 27; ++k) wk[k] = wp[k];
        float b0 = Bias[co];
        float a0 = b0, a1 = b0, a2 = b0, a3 = b0;
        #pragma unroll
        for (int ci = 0; ci < 3; ++ci)
            #pragma unroll
            for (int dy = 0; dy < 3; ++dy)
                #pragma unroll
                for (int dx = 0; dx < 3; ++dx) {
                    float w = wk[ci * 9 + dy * 3 + dx];
                    a0 = fmaf(w, patch[ci][dy][dx],     a0);
                    a1 = fmaf(w, patch[ci][dy][dx + 1], a1);
                    a2 = fmaf(w, patch[ci][dy + 1][dx], a2);
                    a3 = fmaf(w, patch[ci][dy + 1][dx + 1], a3);
                }
        out[out_base + (size_t)co * 4488] = fmaxf(fmaxf(a0, a1), fmaxf(a2, a3));
    }
}

// ------ BN stats: data(32,C,HW_layout) -> a[c], c[c]; count = 32*cnt -------
// Works on padded planes: zeros contribute nothing to s/s2; cnt is true count.
__global__ __launch_bounds__(1024)
void bn_stats_kernel(const float* __restrict__ data, const float* __restrict__ g,
                     const float* __restrict__ b, float* __restrict__ a_out,
                     float* __restrict__ c_out, int C, int HW, int cnt_hw)
{
    const int c = blockIdx.x;
    const int tid = threadIdx.x;
    const int nthr = blockDim.x;
    float s = 0.f, s2 = 0.f;
    for (int n = 0; n < 32; ++n) {
        const float* p = data + (size_t)(n * C + c) * HW;
        for (int i = tid * 4; i < HW; i += 4 * nthr) {
            float4 v = *(const float4*)(p + i);
            s  += v.x + v.y + v.z + v.w;
            s2 += v.x * v.x + v.y * v.y + v.z * v.z + v.w * v.w;
        }
    }
    __shared__ float rs[1024], rs2[1024];
    rs[tid] = s; rs2[tid] = s2;
    __syncthreads();
    for (int off = nthr >> 1; off > 0; off >>= 1) {
        if (tid < off) { rs[tid] += rs[tid + off]; rs2[tid] += rs2[tid + off]; }
        __syncthreads();
    }
    if (tid == 0) {
        float cnt = 32.f * (float)cnt_hw;
        float mean = rs[0] / cnt;
        float var  = rs2[0] / cnt - mean * mean;
        float a = g[c] * rsqrtf(var + 1e-5f);
        a_out[c] = a;
        c_out[c] = b[c] - mean * a;
    }
}

// ---- bn1 in-place on padded1(32,64,66,68): inner=relu(bn(x)), else 0 ------
__global__ __launch_bounds__(256)
void bn_apply_inplace_kernel(float* __restrict__ buf, const float* __restrict__ a,
                             const float* __restrict__ c)
{
    constexpr int PLANE = 66 * 68;
    constexpr int TOTAL = 32 * 64 * PLANE;
    int i = blockIdx.x * 256 + threadIdx.x;
    if (i >= TOTAL) return;
    int nc = i / PLANE;
    int p  = i - nc * PLANE;
    int ch = nc & 63;
    int y = p / 68, x = p - y * 68;
    float v = 0.f;
    if (y >= 1 && y <= 64 && x >= 1 && x <= 64)
        v = fmaxf(fmaf(buf[i], a[ch], c[ch]), 0.f);
    buf[i] = v;
}

// ---- bn2: pool2(32,128,32,32) -> act2(32,128,34,34) = pad0(relu(bn)) ------
__global__ __launch_bounds__(256)
void bn_apply_pad_kernel(const float* __restrict__ pool, const float* __restrict__ a,
                         const float* __restrict__ c, float* __restrict__ act)
{
    constexpr int PLANE = 34 * 34;
    constexpr int TOTAL = 32 * 128 * PLANE;
    int i = blockIdx.x * 256 + threadIdx.x;
    if (i >= TOTAL) return;
    int nc = i / PLANE;
    int p  = i - nc * PLANE;
    int ch = nc & 127;
    int py = p / 34, px = p - py * 34;
    float v = 0.f;
    if (py >= 1 && py <= 32 && px >= 1 && px <= 32)
        v = fmaxf(fmaf(pool[(size_t)nc * 1024 + (py - 1) * 32 + (px - 1)],
                       a[ch], c[ch]), 0.f);
    act[i] = v;
}

// ------------- conv(CIN->128, 3x3 pad1) + maxpool2, DMA-staged -------------
// WIN==64: in = padded1 (32,CIN,66,68), stage 34 rows x 9 float4 per ci.
// WIN==32: in = act2    (32,CIN,34,34), stage = linear copy.
template <int CIN, int WIN, int CO_T>
__global__ __launch_bounds__(256, 4)
void conv_pool_kernel(const float* __restrict__ in, const float* __restrict__ W,
                      const float* __restrict__ Bias, float* __restrict__ out)
{
    constexpr int WOUT   = WIN / 2;
    constexpr int SPT    = WOUT / 16;
    constexpr int CI_T   = 4;
    constexpr int NCHUNK = CIN / CI_T;
    constexpr int LW     = (WIN == 64) ? 36 : 34;    // LDS row width
    constexpr int LCH    = CI_T * 34 * LW;           // LDS floats per chunk
    constexpr int NF4    = (WIN == 64) ? (CI_T * 34 * 9) : (CI_T * 34 * 34 / 4);
    constexpr int NIT    = (NF4 + 255) / 256;

    const int cot = blockIdx.x;
    const int sp  = blockIdx.y;
    const int n   = blockIdx.z;
    const int ty0 = (sp / SPT) * 16, tx0 = (sp % SPT) * 16;
    const int tid = threadIdx.x;
    const int px = tid & 15, py = tid >> 4;

    __shared__ __align__(16) float s_in[2][LCH];

    float acc[CO_T][4];
    #pragma unroll
    for (int co = 0; co < CO_T; ++co) {
        float b0 = Bias[cot * CO_T + co];
        acc[co][0] = b0; acc[co][1] = b0; acc[co][2] = b0; acc[co][3] = b0;
    }

    auto stage = [&](int buf, int ci0) {
        #pragma unroll
        for (int k = 0; k < NIT; ++k) {
            int i4 = tid + 256 * k;
            if (i4 < NF4) {              // active lanes = prefix of each wave
                const float* src;
                if constexpr (WIN == 64) {
                    int ci  = i4 / 306;              // 34*9
                    int rem = i4 - ci * 306;
                    int r   = rem / 9, f = rem - r * 9;
                    src = in + (size_t)(n * CIN + ci0 + ci) * 4488
                             + (size_t)(2 * ty0 + r) * 68 + 2 * tx0 + 4 * f;
                } else {
                    src = in + (size_t)(n * CIN + ci0) * 1156 + 4 * i4;
                }
                __builtin_amdgcn_global_load_lds(
                    (const __attribute__((address_space(1))) float*)src,
                    (__attribute__((address_space(3))) float*)(&s_in[buf][0] + 4 * i4),
                    16, 0, 0);
            }
        }
    };

    stage(0, 0);
    __syncthreads();                                 // vmcnt(0) drain

    const float* Wbase = W + (size_t)(cot * CO_T) * CIN * 9;

    #pragma unroll 1
    for (int c = 0; c < NCHUNK; ++c) {
        if (c + 1 < NCHUNK) stage((c + 1) & 1, (c + 1) * CI_T);   // async issue
        const float* sbuf = &s_in[c & 1][0];
        #pragma unroll
        for (int ci = 0; ci < CI_T; ++ci) {
            float patch[4][4];
            #pragma unroll
            for (int r = 0; r < 4; ++r) {
                const float* rowp = sbuf + (ci * 34 + 2 * py + r) * LW + 2 * px;
                float2 a = *(const float2*)rowp;
                float2 b = *(const float2*)(rowp + 2);
                patch[r][0] = a.x; patch[r][1] = a.y;
                patch[r][2] = b.x; patch[r][3] = b.y;
            }
            const float* wp = Wbase + (size_t)(c * CI_T + ci) * 9;
            #pragma unroll
            for (int co = 0; co < CO_T; ++co) {
                float wk[9];                         // wave-uniform -> s_load
                #pragma unroll
                for (int k = 0; k < 9; ++k) wk[k] = wp[(size_t)co * CIN * 9 + k];
                #pragma unroll
                for (int dy = 0; dy < 3; ++dy)
                    #pragma unroll
                    for (int dx = 0; dx < 3; ++dx) {
                        float w = wk[dy * 3 + dx];
                        acc[co][0] = fmaf(w, patch[dy][dx],         acc[co][0]);
                        acc[co][1] = fmaf(w, patch[dy][dx + 1],     acc[co][1]);
                        acc[co][2] = fmaf(w, patch[dy + 1][dx],     acc[co][2]);
                        acc[co][3] = fmaf(w, patch[dy + 1][dx + 1], acc[co][3]);
                    }
            }
        }
        __syncthreads();   // drains next chunk's DMA + protects buffer reuse
    }

    const size_t out_base = (size_t)(n * 128 + cot * CO_T) * (WOUT * WOUT)
                          + (ty0 + py) * WOUT + tx0 + px;
    #pragma unroll
    for (int co = 0; co < CO_T; ++co) {
        float m = fmaxf(fmaxf(acc[co][0], acc[co][1]), fmaxf(acc[co][2], acc[co][3]));
        out[out_base + (size_t)co * (WOUT * WOUT)] = m;
    }
}

// ---------------- VIN head: one block per image ----------------------------
__global__ __launch_bounds__(256)
void vin_kernel(const float* __restrict__ pool3, const float* __restrict__ bn_a,
                const float* __restrict__ bn_c, const float* __restrict__ r_w,
                const float* __restrict__ q_w, const float* __restrict__ w_vi,
                const float* __restrict__ crit_w, const float* __restrict__ crit_b,
                const int* __restrict__ Kp, float* __restrict__ out_critic,
                float* __restrict__ out_q)
{
    const int n = blockIdx.x;
    const int tid = threadIdx.x;           // 256 = 16x16 positions
    const int px = tid & 15, py = tid >> 4;

    __shared__ float s_cr[16][256];        // conv_r[co][pos]
    __shared__ float s_v[20][20];          // padded plane (r, then v)
    __shared__ float s_qw[16][25];
    __shared__ float s_wvi[16][25];
    __shared__ float s_rw[128];
    __shared__ float s_red[256];

    for (int i = tid; i < 400; i += 256) {
        s_qw[i / 25][i % 25]  = q_w[i];
        s_wvi[i / 25][i % 25] = w_vi[i];
        s_v[i / 20][i % 20]   = 0.f;
    }
    if (tid < 128) s_rw[tid] = r_w[tid];
    __syncthreads();

    // r[pos] = sum_ci relu(bn3(pool3)) * r_w[ci]
    float r = 0.f;
    const float* p3 = pool3 + (size_t)n * 128 * 256 + tid;
    #pragma unroll 4
    for (int ci = 0; ci < 128; ++ci) {
        float x = p3[ci * 256];
        x = fmaxf(fmaf(x, bn_a[ci], bn_c[ci]), 0.f);
        r = fmaf(x, s_rw[ci], r);
    }
    s_v[py + 2][px + 2] = r;               // padded r plane
    __syncthreads();

    // conv_r = conv5x5(r, q_w), initial v = max_co conv_r
    float cr[16];
    #pragma unroll
    for (int co = 0; co < 16; ++co) cr[co] = 0.f;
    #pragma unroll
    for (int dy = 0; dy < 5; ++dy)
        #pragma unroll
        for (int dx = 0; dx < 5; ++dx) {
            float rv = s_v[py + dy][px + dx];
            #pragma unroll
            for (int co = 0; co < 16; ++co)
                cr[co] = fmaf(s_qw[co][dy * 5 + dx], rv, cr[co]);
        }
    float v = cr[0];
    #pragma unroll
    for (int co = 0; co < 16; ++co) { s_cr[co][tid] = cr[co]; v = fmaxf(v, cr[co]); }
    __syncthreads();                       // all reads of r plane done
    s_v[py + 2][px + 2] = v;
    __syncthreads();

    const int K = Kp[0];
    float q[16];
    #pragma unroll 1
    for (int it = 0; it < K; ++it) {
        #pragma unroll
        for (int co = 0; co < 16; ++co) q[co] = s_cr[co][tid];
        #pragma unroll
        for (int dy = 0; dy < 5; ++dy)
            #pragma unroll
            for (int dx = 0; dx < 5; ++dx) {
                float vv = s_v[py + dy][px + dx];
                #pragma unroll
                for (int co = 0; co < 16; ++co)
                    q[co] = fmaf(s_wvi[co][dy * 5 + dx], vv, q[co]);
            }
        float nv = q[0];
        #pragma unroll
        for (int co = 1; co < 16; ++co) nv = fmaxf(nv, q[co]);
        __syncthreads();                   // all reads of old v done
        s_v[py + 2][px + 2] = nv;
        __syncthreads();                   // new v visible
        v = nv;
    }

    // q output: (B, 16, 16, 16) -> flat 4096 per image
    #pragma unroll
    for (int co = 0; co < 16; ++co)
        out_q[(size_t)n * 4096 + co * 256 + tid] = q[co];

    // critic[n] = sum_pos v*crit_w + crit_b
    s_red[tid] = v * crit_w[tid];
    __syncthreads();
    for (int off = 128; off > 0; off >>= 1) {
        if (tid < off) s_red[tid] += s_red[tid + off];
        __syncthreads();
    }
    if (tid == 0) out_critic[n] = s_red[0] + crit_b[0];
}

// ---------------------------------------------------------------------------
extern "C" void kernel_launch(void* const* d_in, const int* in_sizes, int n_in,
                              void* d_out, int out_size, void* d_ws, size_t ws_size,
                              hipStream_t stream)
{
    const float* X      = (const float*)d_in[0];
    // d_in[1] = obs (unused)
    const float* h1_w   = (const float*)d_in[2];
    const float* h1_b   = (const float*)d_in[3];
    const float* bn1_g  = (const float*)d_in[4];
    const float* bn1_b  = (const float*)d_in[5];
    const float* h2_w   = (const float*)d_in[6];
    const float* h2_b   = (const float*)d_in[7];
    const float* bn2_g  = (const float*)d_in[8];
    const float* bn2_b  = (const float*)d_in[9];
    const float* h3_w   = (const float*)d_in[10];
    const float* h3_b   = (const float*)d_in[11];
    const float* bn3_g  = (const float*)d_in[12];
    const float* bn3_b  = (const float*)d_in[13];
    const float* r_w    = (const float*)d_in[14];
    const float* q_w    = (const float*)d_in[15];
    const float* w_vi   = (const float*)d_in[16];
    const float* crit_w = (const float*)d_in[17];
    const float* crit_b = (const float*)d_in[18];
    const int*   Kp     = (const int*)d_in[19];

    // workspace (floats); high-water 13,386,368 floats = 53.5 MB
    float* ws      = (float*)d_ws;
    float* padded1 = ws;                       // [0, 9191424)  32*64*66*68
    float* pool2   = ws + 9191424;             // [9191424, 13385728) 32*128*32*32
    float* act2    = ws;                       // [0, 4734976)  32*128*34*34
                                               //   (padded1 dead after conv2)
    float* pool3   = ws + 4734976;             // [4734976, 5783552) 32*128*16*16
    float* bn1a    = ws + 13385728;            // params after pool2
    float* bn1c    = bn1a + 64;
    float* bn2a    = bn1c + 64;
    float* bn2c    = bn2a + 128;
    float* bn3a    = bn2c + 128;
    float* bn3c    = bn3a + 128;

    float* out_critic = (float*)d_out;         // 32
    float* out_q      = out_critic + 32;       // 32*4096

    // zero padded1 so borders are defined (stats read zeros; DMA reads zeros)
    hipMemsetAsync(padded1, 0, (size_t)9191424 * sizeof(float), stream);

    conv1_pool_kernel<<<dim3(16, 32), 256, 0, stream>>>(X, h1_w, h1_b, padded1);
    bn_stats_kernel<<<64, 1024, 0, stream>>>(padded1, bn1_g, bn1_b, bn1a, bn1c,
                                             64, 4488, 4096);
    bn_apply_inplace_kernel<<<(32 * 64 * 4488 + 255) / 256, 256, 0, stream>>>(
        padded1, bn1a, bn1c);
    conv_pool_kernel<64, 64, 16><<<dim3(8, 4, 32), 256, 0, stream>>>(
        padded1, h2_w, h2_b, pool2);
    bn_stats_kernel<<<128, 1024, 0, stream>>>(pool2, bn2_g, bn2_b, bn2a, bn2c,
                                              128, 1024, 1024);
    bn_apply_pad_kernel<<<(32 * 128 * 1156 + 255) / 256, 256, 0, stream>>>(
        pool2, bn2a, bn2c, act2);
    conv_pool_kernel<128, 32, 4><<<dim3(32, 1, 32), 256, 0, stream>>>(
        act2, h3_w, h3_b, pool3);
    bn_stats_kernel<<<128, 1024, 0, stream>>>(pool3, bn3_g, bn3_b, bn3a, bn3c,
                                              128, 256, 256);
    vin_kernel<<<32, 256, 0, stream>>>(pool3, bn3a, bn3c, r_w, q_w, w_vi,
                                       crit_w, crit_b, Kp, out_critic, out_q);
}

// Round 10
// 777.492 us; speedup vs baseline: 1.8516x; 1.0613x over previous
//
#include <hip/hip_runtime.h>
#include <hip/hip_bf16.h>

// ---------------------------------------------------------------------------
// VIN forward (r10): conv2/conv3 on MATRIX CORES (split-bf16 implicit GEMM).
// Measured history: r4 1047us (fp32 latency-bound) -> r9 825us (DMA dbuf,
// VALU 76%, conv ~445us vs 123us fp32-FMA floor -> vector path capped).
// r10: NHWC everywhere. conv2/conv3 = MFMA 16x16x32_bf16 implicit GEMM:
//   A = activations staged f32->bf16(hi,lo) into XOR-swizzled LDS tiles,
//   B = weights pretransformed Wt[co][tap][ci] bf16 hi/lo read from global,
//   acc += Ah*Wh + Al*Wh + Ah*Wl  (error ~2^-16: fp32-class accuracy).
//   Epilogue: in-register h-pool, shfl_xor(32) v-pool, +bias, NHWC store.
// BN: partial-sum + finalize kernels (NHWC), apply = elementwise in-place.
// Workspace high-water 51.5 MB (< 54.5 MB proven in r4).
// ---------------------------------------------------------------------------

using bf16x8 = __attribute__((ext_vector_type(8))) short;
using f32x4  = __attribute__((ext_vector_type(4))) float;

__device__ __forceinline__ unsigned short f2bf(float x) {
    union { float f; unsigned u; } v; v.f = x;
    unsigned r = (v.u + 0x7FFFu + ((v.u >> 16) & 1u)) >> 16;
    return (unsigned short)r;
}
__device__ __forceinline__ float bfhi(unsigned short h) {
    union { unsigned u; float f; } v; v.u = ((unsigned)h) << 16;
    return v.f;
}

// ---- weight transform: W[co][ci][3][3] f32 -> Wt[co][tap][ci] bf16 hi/lo --
template <int CIN>
__global__ __launch_bounds__(256)
void wt_kernel(const float* __restrict__ W, short* __restrict__ Wh,
               short* __restrict__ Wl)
{
    constexpr int TOTAL = 128 * CIN * 9;
    int i = blockIdx.x * 256 + threadIdx.x;
    if (i >= TOTAL) return;
    int ci = i & (CIN - 1);
    int j  = i / CIN;            // j = co*9 + tap
    int tap = j % 9, co = j / 9;
    float x = W[(co * CIN + ci) * 9 + tap];
    unsigned short h = f2bf(x);
    Wh[i] = (short)h;
    Wl[i] = (short)f2bf(x - bfhi(h));
}

// ------- conv1: X(32,3,128,128) -> pool1 NHWC f32 (32,64,64,64ci) ----------
__global__ __launch_bounds__(256)
void conv1_pool_kernel(const float* __restrict__ X, const float* __restrict__ W,
                       const float* __restrict__ Bias, float* __restrict__ out)
{
    const int sp  = blockIdx.x;          // 16 spatial tiles (4x4 of 16x16 pooled)
    const int n   = blockIdx.y;
    const int ty0 = (sp >> 2) * 16;
    const int tx0 = (sp & 3) * 16;
    const int tid = threadIdx.x;
    const int px = tid & 15, py = tid >> 4;

    __shared__ float s_in[3][34][34];

    const int gy0 = 2 * ty0 - 1, gx0 = 2 * tx0 - 1;
    for (int idx = tid; idx < 3 * 1156; idx += 256) {
        int ci = idx / 1156, rem = idx - ci * 1156;
        int ly = rem / 34, lx = rem - ly * 34;
        int gy = gy0 + ly, gx = gx0 + lx;
        float v = 0.f;
        if ((unsigned)gy < 128u && (unsigned)gx < 128u)
            v = X[((n * 3 + ci) << 14) + (gy << 7) + gx];
        s_in[ci][ly][lx] = v;
    }
    __syncthreads();

    float patch[3][4][4];
    #pragma unroll
    for (int ci = 0; ci < 3; ++ci)
        #pragma unroll
        for (int r = 0; r < 4; ++r) {
            float2 a = *(const float2*)&s_in[ci][2 * py + r][2 * px];
            float2 b = *(const float2*)&s_in[ci][2 * py + r][2 * px + 2];
            patch[ci][r][0] = a.x; patch[ci][r][1] = a.y;
            patch[ci][r][2] = b.x; patch[ci][r][3] = b.y;
        }

    // NHWC out: [n][pyp][pxp][co]
    float* obase = out + (((size_t)(n * 64 + ty0 + py) * 64) + tx0 + px) * 64;
    #pragma unroll 1
    for (int co0 = 0; co0 < 64; co0 += 4) {
        float4 res;
        #pragma unroll
        for (int j = 0; j < 4; ++j) {
            int co = co0 + j;
            float wk[27];                // wave-uniform -> s_load
            const float* wp = W + co * 27;
            #pragma unroll
            for (int k = 0; k < 27; ++k) wk[k] = wp[k];
            float b0 = Bias[co];
            float a0 = b0, a1 = b0, a2 = b0, a3 = b0;
            #pragma unroll
            for (int ci = 0; ci < 3; ++ci)
                #pragma unroll
                for (int dy = 0; dy < 3; ++dy)
                    #pragma unroll
                    for (int dx = 0; dx < 3; ++dx) {
                        float w = wk[ci * 9 + dy * 3 + dx];
                        a0 = fmaf(w, patch[ci][dy][dx],     a0);
                        a1 = fmaf(w, patch[ci][dy][dx + 1], a1);
                        a2 = fmaf(w, patch[ci][dy + 1][dx], a2);
                        a3 = fmaf(w, patch[ci][dy + 1][dx + 1], a3);
                    }
            float m = fmaxf(fmaxf(a0, a1), fmaxf(a2, a3));
            if (j == 0) res.x = m; else if (j == 1) res.y = m;
            else if (j == 2) res.z = m; else res.w = m;
        }
        *(float4*)(obase + co0) = res;
    }
}

// ---- BN stats stage 1: NHWC data -> partials[b][C][2] (sum, sumsq) --------
template <int C>
__global__ __launch_bounds__(256)
void bn_partial_kernel(const float* __restrict__ data, int total,
                       float* __restrict__ partials)
{
    const int b = blockIdx.x, t = threadIdx.x;
    float s = 0.f, s2 = 0.f;
    for (int i = b * 256 + t; i < total; i += 256 * 256) {
        float v = data[i];
        s += v; s2 += v * v;
    }
    __shared__ float rs[256], rs2[256];
    rs[t] = s; rs2[t] = s2;
    __syncthreads();
    if (t < C) {
        #pragma unroll
        for (int off = C; off < 256; off += C) { s += rs[t + off]; s2 += rs2[t + off]; }
        partials[(b * C + t) * 2]     = s;
        partials[(b * C + t) * 2 + 1] = s2;
    }
}

// ---- BN stats stage 2: reduce partials -> a[c], c[c] ----------------------
__global__ __launch_bounds__(128)
void bn_finalize_kernel(const float* __restrict__ partials, int C, float cnt,
                        const float* __restrict__ g, const float* __restrict__ bb,
                        float* __restrict__ a_out, float* __restrict__ c_out)
{
    int t = threadIdx.x;
    if (t >= C) return;
    float s = 0.f, s2 = 0.f;
    for (int i = 0; i < 256; ++i) {
        s  += partials[(i * C + t) * 2];
        s2 += partials[(i * C + t) * 2 + 1];
    }
    float mean = s / cnt;
    float var  = s2 / cnt - mean * mean;
    float a = g[t] * rsqrtf(var + 1e-5f);
    a_out[t] = a;
    c_out[t] = bb[t] - mean * a;
}

// ---- BN apply in place on NHWC buffer: x = relu(a*x + c) ------------------
template <int C>
__global__ __launch_bounds__(256)
void bn_apply_kernel(float* __restrict__ buf, int total,
                     const float* __restrict__ a, const float* __restrict__ c)
{
    int i = blockIdx.x * 256 + threadIdx.x;
    if (i >= total) return;
    int ci = i & (C - 1);
    buf[i] = fmaxf(fmaf(buf[i], a[ci], c[ci]), 0.f);
}

// ---- MFMA conv(CIN->128, 3x3 pad1) + pool2 + bias, split-bf16 -------------
// in: NHWC f32 (32, WIN, WIN, CIN). out: NHWC f32 (32, WIN/2, WIN/2, 128).
template <int CIN, int WIN>
__global__ __launch_bounds__(256, 4)
void conv_mfma_kernel(const float* __restrict__ in, const short* __restrict__ Wth,
                      const short* __restrict__ Wtl, const float* __restrict__ Bias,
                      float* __restrict__ out)
{
    constexpr int CC  = CIN / 32;          // K chunks of 32 ci
    constexpr int POW = WIN / 2;
    constexpr int LT  = (WIN == 64) ? 3 : 2;
    const int bx = blockIdx.x;
    const int n  = blockIdx.y;
    const int ty = bx >> LT, tx = bx & ((1 << LT) - 1);
    const int y0 = ty * 8, x0 = tx * 8;    // 8x8 pre-pool pixel tile
    const int tid  = threadIdx.x;
    const int w    = tid >> 6;             // wave id = M-frag
    const int lane = tid & 63;

    // A tiles: [buf][hi/lo][100 pixels x 32 ci] bf16, 16B-slot XOR swizzle
    __shared__ __align__(16) short smem[2][2][3200];

    auto stage = [&](int buf, int c) {
        #pragma unroll
        for (int rep = 0; rep < 2; ++rep) {
            int u = tid + rep * 256;
            if (u < 400) {                  // unit = (halo point, 8-ci slot)
                int p = u >> 2, slot = u & 3;
                int hy = p / 10, hx = p - hy * 10;
                int y = y0 - 1 + hy, x = x0 - 1 + hx;
                float4 f0 = make_float4(0.f, 0.f, 0.f, 0.f);
                float4 f1 = make_float4(0.f, 0.f, 0.f, 0.f);
                if ((unsigned)y < (unsigned)WIN && (unsigned)x < (unsigned)WIN) {
                    const float* s = in + (size_t)((n * WIN + y) * WIN + x) * CIN
                                   + c * 32 + slot * 8;
                    f0 = *(const float4*)s;
                    f1 = *(const float4*)(s + 4);
                }
                float vs0[4] = {f0.x, f0.y, f0.z, f0.w};
                float vs1[4] = {f1.x, f1.y, f1.z, f1.w};
                unsigned hpk[4], lpk[4];
                #pragma unroll
                for (int q = 0; q < 4; ++q) {
                    float e0 = (q < 2) ? vs0[2 * q] : vs1[2 * (q - 2)];
                    float e1 = (q < 2) ? vs0[2 * q + 1] : vs1[2 * (q - 2) + 1];
                    unsigned short h0 = f2bf(e0), h1 = f2bf(e1);
                    unsigned short l0 = f2bf(e0 - bfhi(h0));
                    unsigned short l1 = f2bf(e1 - bfhi(h1));
                    hpk[q] = (unsigned)h0 | ((unsigned)h1 << 16);
                    lpk[q] = (unsigned)l0 | ((unsigned)l1 << 16);
                }
                int off = p * 32 + ((slot ^ (p & 3)) << 3);      // shorts
                *(int4*)&smem[buf][0][off] =
                    make_int4((int)hpk[0], (int)hpk[1], (int)hpk[2], (int)hpk[3]);
                *(int4*)&smem[buf][1][off] =
                    make_int4((int)lpk[0], (int)lpk[1], (int)lpk[2], (int)lpk[3]);
            }
        }
    };

    f32x4 acc[8];
    #pragma unroll
    for (int nf = 0; nf < 8; ++nf) acc[nf] = (f32x4){0.f, 0.f, 0.f, 0.f};

    // per-lane fragment constants
    const int yloc = 2 * w + ((lane & 15) >> 3);   // A-frag row -> tile y'
    const int xloc = lane & 7;                     // tile x'
    const int seg  = lane >> 4;                    // 8-ci k segment

    stage(0, 0);
    __syncthreads();

    #pragma unroll 1
    for (int c = 0; c < CC; ++c) {
        if (c + 1 < CC) stage((c + 1) & 1, c + 1);
        const short* Ah = &smem[c & 1][0][0];
        const short* Al = &smem[c & 1][1][0];
        #pragma unroll
        for (int tap = 0; tap < 9; ++tap) {
            const int dy = tap / 3, dx = tap % 3;
            const int lp = (yloc + dy) * 10 + (xloc + dx);
            const int aoff = lp * 32 + ((seg ^ (lp & 3)) << 3);
            bf16x8 ah = *(const bf16x8*)(Ah + aoff);
            bf16x8 al = *(const bf16x8*)(Al + aoff);
            #pragma unroll
            for (int nf = 0; nf < 8; ++nf) {
                int co = nf * 16 + (lane & 15);
                const short* wp = Wth + ((size_t)(co * 9 + tap)) * CIN + c * 32 + seg * 8;
                const short* wq = Wtl + ((size_t)(co * 9 + tap)) * CIN + c * 32 + seg * 8;
                bf16x8 bh = *(const bf16x8*)wp;
                bf16x8 bl = *(const bf16x8*)wq;
                acc[nf] = __builtin_amdgcn_mfma_f32_16x16x32_bf16(ah, bh, acc[nf], 0, 0, 0);
                acc[nf] = __builtin_amdgcn_mfma_f32_16x16x32_bf16(al, bh, acc[nf], 0, 0, 0);
                acc[nf] = __builtin_amdgcn_mfma_f32_16x16x32_bf16(ah, bl, acc[nf], 0, 0, 0);
            }
        }
        __syncthreads();
    }

    // epilogue: h-pool in-register, v-pool via lane^32, +bias, NHWC store
    const int g = lane >> 4;
    const int ypo = (y0 >> 1) + w;
    const int xpo = (x0 >> 1) + (g & 1) * 2;
    #pragma unroll
    for (int nf = 0; nf < 8; ++nf) {
        int co = nf * 16 + (lane & 15);
        float bv = Bias[co];
        float h0 = fmaxf(acc[nf][0], acc[nf][1]);
        float h1 = fmaxf(acc[nf][2], acc[nf][3]);
        float o0 = fmaxf(h0, __shfl_xor(h0, 32));
        float o1 = fmaxf(h1, __shfl_xor(h1, 32));
        if (g < 2) {
            float* ob = out + (size_t)((n * POW + ypo) * POW + xpo) * 128 + co;
            ob[0]   = o0 + bv;
            ob[128] = o1 + bv;   // xpo+1 -> +C
        }
    }
}

// ---------------- VIN head: one block per image (NHWC pool3) ---------------
__global__ __launch_bounds__(256)
void vin_kernel(const float* __restrict__ pool3, const float* __restrict__ bn_a,
                const float* __restrict__ bn_c, const float* __restrict__ r_w,
                const float* __restrict__ q_w, const float* __restrict__ w_vi,
                const float* __restrict__ crit_w, const float* __restrict__ crit_b,
                const int* __restrict__ Kp, float* __restrict__ out_critic,
                float* __restrict__ out_q)
{
    const int n = blockIdx.x;
    const int tid = threadIdx.x;           // 256 = 16x16 positions
    const int px = tid & 15, py = tid >> 4;

    __shared__ float s_cr[16][256];
    __shared__ float s_v[20][20];
    __shared__ float s_qw[16][25];
    __shared__ float s_wvi[16][25];
    __shared__ float s_rw[128];
    __shared__ float s_red[256];

    for (int i = tid; i < 400; i += 256) {
        s_qw[i / 25][i % 25]  = q_w[i];
        s_wvi[i / 25][i % 25] = w_vi[i];
        s_v[i / 20][i % 20]   = 0.f;
    }
    if (tid < 128) s_rw[tid] = r_w[tid];
    __syncthreads();

    // r[pos] = sum_ci relu(bn3(pool3)) * r_w[ci]   (pool3 NHWC: per-thread row)
    float r = 0.f;
    const float* p3 = pool3 + ((size_t)n * 256 + tid) * 128;
    #pragma unroll 1
    for (int ci0 = 0; ci0 < 128; ci0 += 4) {
        float4 v4 = *(const float4*)(p3 + ci0);
        float e[4] = {v4.x, v4.y, v4.z, v4.w};
        #pragma unroll
        for (int j = 0; j < 4; ++j) {
            float x = fmaxf(fmaf(e[j], bn_a[ci0 + j], bn_c[ci0 + j]), 0.f);
            r = fmaf(x, s_rw[ci0 + j], r);
        }
    }
    s_v[py + 2][px + 2] = r;
    __syncthreads();

    float cr[16];
    #pragma unroll
    for (int co = 0; co < 16; ++co) cr[co] = 0.f;
    #pragma unroll
    for (int dy = 0; dy < 5; ++dy)
        #pragma unroll
        for (int dx = 0; dx < 5; ++dx) {
            float rv = s_v[py + dy][px + dx];
            #pragma unroll
            for (int co = 0; co < 16; ++co)
                cr[co] = fmaf(s_qw[co][dy * 5 + dx], rv, cr[co]);
        }
    float v = cr[0];
    #pragma unroll
    for (int co = 0; co < 16; ++co) { s_cr[co][tid] = cr[co]; v = fmaxf(v, cr[co]); }
    __syncthreads();
    s_v[py + 2][px + 2] = v;
    __syncthreads();

    const int K = Kp[0];
    float q[16];
    #pragma unroll 1
    for (int it = 0; it < K; ++it) {
        #pragma unroll
        for (int co = 0; co < 16; ++co) q[co] = s_cr[co][tid];
        #pragma unroll
        for (int dy = 0; dy < 5; ++dy)
            #pragma unroll
            for (int dx = 0; dx < 5; ++dx) {
                float vv = s_v[py + dy][px + dx];
                #pragma unroll
                for (int co = 0; co < 16; ++co)
                    q[co] = fmaf(s_wvi[co][dy * 5 + dx], vv, q[co]);
            }
        float nv = q[0];
        #pragma unroll
        for (int co = 1; co < 16; ++co) nv = fmaxf(nv, q[co]);
        __syncthreads();
        s_v[py + 2][px + 2] = nv;
        __syncthreads();
        v = nv;
    }

    #pragma unroll
    for (int co = 0; co < 16; ++co)
        out_q[(size_t)n * 4096 + co * 256 + tid] = q[co];

    s_red[tid] = v * crit_w[tid];
    __syncthreads();
    for (int off = 128; off > 0; off >>= 1) {
        if (tid < off) s_red[tid] += s_red[tid + off];
        __syncthreads();
    }
    if (tid == 0) out_critic[n] = s_red[0] + crit_b[0];
}

// ---------------------------------------------------------------------------
extern "C" void kernel_launch(void* const* d_in, const int* in_sizes, int n_in,
                              void* d_out, int out_size, void* d_ws, size_t ws_size,
                              hipStream_t stream)
{
    const float* X      = (const float*)d_in[0];
    // d_in[1] = obs (unused)
    const float* h1_w   = (const float*)d_in[2];
    const float* h1_b   = (const float*)d_in[3];
    const float* bn1_g  = (const float*)d_in[4];
    const float* bn1_b  = (const float*)d_in[5];
    const float* h2_w   = (const float*)d_in[6];
    const float* h2_b   = (const float*)d_in[7];
    const float* bn2_g  = (const float*)d_in[8];
    const float* bn2_b  = (const float*)d_in[9];
    const float* h3_w   = (const float*)d_in[10];
    const float* h3_b   = (const float*)d_in[11];
    const float* bn3_g  = (const float*)d_in[12];
    const float* bn3_b  = (const float*)d_in[13];
    const float* r_w    = (const float*)d_in[14];
    const float* q_w    = (const float*)d_in[15];
    const float* w_vi   = (const float*)d_in[16];
    const float* crit_w = (const float*)d_in[17];
    const float* crit_b = (const float*)d_in[18];
    const int*   Kp     = (const int*)d_in[19];

    // workspace (floats); high-water 12,870,656 fl = 51.5 MB (< 54.5 proven)
    float* ws    = (float*)d_ws;
    short* W2H   = (short*)(ws);            // 73728 shorts  (36864 fl)
    short* W2L   = (short*)(ws + 36864);
    short* W3H   = (short*)(ws + 73728);    // 147456 shorts (73728 fl)
    short* W3L   = (short*)(ws + 147456);
    float* part  = ws + 221184;             // 256*128*2 = 65536 fl
    float* prm   = ws + 286720;             // bn params (1024 fl)
    float* a1 = prm, *c1 = prm + 64, *a2 = prm + 128, *c2 = prm + 256,
         * a3 = prm + 384, *c3 = prm + 512;
    float* buf1  = ws + 287744;             // 32*64*64*64  = 8388608 fl (NHWC)
    float* buf2  = ws + 8676352;            // 32*32*32*128 = 4194304 fl (NHWC)
    float* pool3 = ws + 287744;             // 32*16*16*128 = 1048576 fl
                                            //  (aliases buf1: dead during conv3)

    float* out_critic = (float*)d_out;      // 32
    float* out_q      = out_critic + 32;    // 32*4096

    wt_kernel<64><<<(128 * 64 * 9 + 255) / 256, 256, 0, stream>>>(h2_w, W2H, W2L);
    wt_kernel<128><<<(128 * 128 * 9 + 255) / 256, 256, 0, stream>>>(h3_w, W3H, W3L);

    conv1_pool_kernel<<<dim3(16, 32), 256, 0, stream>>>(X, h1_w, h1_b, buf1);

    bn_partial_kernel<64><<<256, 256, 0, stream>>>(buf1, 8388608, part);
    bn_finalize_kernel<<<1, 128, 0, stream>>>(part, 64, 131072.f, bn1_g, bn1_b, a1, c1);
    bn_apply_kernel<64><<<(8388608 + 255) / 256, 256, 0, stream>>>(buf1, 8388608, a1, c1);

    conv_mfma_kernel<64, 64><<<dim3(64, 32), 256, 0, stream>>>(buf1, W2H, W2L, h2_b, buf2);

    bn_partial_kernel<128><<<256, 256, 0, stream>>>(buf2, 4194304, part);
    bn_finalize_kernel<<<1, 128, 0, stream>>>(part, 128, 32768.f, bn2_g, bn2_b, a2, c2);
    bn_apply_kernel<128><<<(4194304 + 255) / 256, 256, 0, stream>>>(buf2, 4194304, a2, c2);

    conv_mfma_kernel<128, 32><<<dim3(16, 32), 256, 0, stream>>>(buf2, W3H, W3L, h3_b, pool3);

    bn_partial_kernel<128><<<256, 256, 0, stream>>>(pool3, 1048576, part);
    bn_finalize_kernel<<<1, 128, 0, stream>>>(part, 128, 8192.f, bn3_g, bn3_b, a3, c3);

    vin_kernel<<<32, 256, 0, stream>>>(pool3, a3, c3, r_w, q_w, w_vi,
                                       crit_w, crit_b, Kp, out_critic, out_q);
}

// Round 11
// 507.127 us; speedup vs baseline: 2.8388x; 1.5331x over previous
//
#include <hip/hip_runtime.h>
#include <hip/hip_bf16.h>

// ---------------------------------------------------------------------------
// VIN forward (r11): MFMA implicit GEMM with amortized fragments.
// History: r9 825us fp32 (VALU-capped) -> r10 777us MFMA (conv2 272us but
//   MfmaUtil 8.5%, VALU 5.6%, VGPR 64 => latency-bound: 2 global B-loads per
//   3 MFMAs, no prefetch headroom).
// r11: 16x16 px x 64 co per block; wave = 4 M-frags x 4 N-frags (acc 64 VGPR).
//   Per tap: 8 A ds_reads + 8 B loads feed 48 MFMAs (3x better ratio).
//   Seg-major A-LDS layout (conflict-free contiguous 16B reads/writes).
//   bn+relu fused into conv staging (bn_apply passes deleted).
//   v-pool in-register across mf frags (no shfl, all lanes store).
//   launch_bounds(256,3): VGPR cap ~170, LDS 41.5KB -> 3 blocks/CU.
// ---------------------------------------------------------------------------

using bf16x8 = __attribute__((ext_vector_type(8))) short;
using f32x4  = __attribute__((ext_vector_type(4))) float;

__device__ __forceinline__ unsigned short f2bf(float x) {
    union { float f; unsigned u; } v; v.f = x;
    unsigned r = (v.u + 0x7FFFu + ((v.u >> 16) & 1u)) >> 16;
    return (unsigned short)r;
}
__device__ __forceinline__ float bfhi(unsigned short h) {
    union { unsigned u; float f; } v; v.u = ((unsigned)h) << 16;
    return v.f;
}

// ---- weight transform: W[co][ci][3][3] f32 -> Wt[co][tap][ci] bf16 hi/lo --
template <int CIN>
__global__ __launch_bounds__(256)
void wt_kernel(const float* __restrict__ W, short* __restrict__ Wh,
               short* __restrict__ Wl)
{
    constexpr int TOTAL = 128 * CIN * 9;
    int i = blockIdx.x * 256 + threadIdx.x;
    if (i >= TOTAL) return;
    int ci = i & (CIN - 1);
    int j  = i / CIN;            // j = co*9 + tap
    int tap = j % 9, co = j / 9;
    float x = W[(co * CIN + ci) * 9 + tap];
    unsigned short h = f2bf(x);
    Wh[i] = (short)h;
    Wl[i] = (short)f2bf(x - bfhi(h));
}

// ------- conv1: X(32,3,128,128) -> pool1 NHWC f32 (32,64,64,64ci) ----------
__global__ __launch_bounds__(256)
void conv1_pool_kernel(const float* __restrict__ X, const float* __restrict__ W,
                       const float* __restrict__ Bias, float* __restrict__ out)
{
    const int sp  = blockIdx.x;
    const int n   = blockIdx.y;
    const int ty0 = (sp >> 2) * 16;
    const int tx0 = (sp & 3) * 16;
    const int tid = threadIdx.x;
    const int px = tid & 15, py = tid >> 4;

    __shared__ float s_in[3][34][34];

    const int gy0 = 2 * ty0 - 1, gx0 = 2 * tx0 - 1;
    for (int idx = tid; idx < 3 * 1156; idx += 256) {
        int ci = idx / 1156, rem = idx - ci * 1156;
        int ly = rem / 34, lx = rem - ly * 34;
        int gy = gy0 + ly, gx = gx0 + lx;
        float v = 0.f;
        if ((unsigned)gy < 128u && (unsigned)gx < 128u)
            v = X[((n * 3 + ci) << 14) + (gy << 7) + gx];
        s_in[ci][ly][lx] = v;
    }
    __syncthreads();

    float patch[3][4][4];
    #pragma unroll
    for (int ci = 0; ci < 3; ++ci)
        #pragma unroll
        for (int r = 0; r < 4; ++r) {
            float2 a = *(const float2*)&s_in[ci][2 * py + r][2 * px];
            float2 b = *(const float2*)&s_in[ci][2 * py + r][2 * px + 2];
            patch[ci][r][0] = a.x; patch[ci][r][1] = a.y;
            patch[ci][r][2] = b.x; patch[ci][r][3] = b.y;
        }

    float* obase = out + (((size_t)(n * 64 + ty0 + py) * 64) + tx0 + px) * 64;
    #pragma unroll 1
    for (int co0 = 0; co0 < 64; co0 += 4) {
        float4 res;
        #pragma unroll
        for (int j = 0; j < 4; ++j) {
            int co = co0 + j;
            float wk[27];                // wave-uniform -> s_load
            const float* wp = W + co * 27;
            #pragma unroll
            for (int k = 0; k < 27; ++k) wk[k] = wp[k];
            float b0 = Bias[co];
            float a0 = b0, a1 = b0, a2 = b0, a3 = b0;
            #pragma unroll
            for (int ci = 0; ci < 3; ++ci)
                #pragma unroll
                for (int dy = 0; dy < 3; ++dy)
                    #pragma unroll
                    for (int dx = 0; dx < 3; ++dx) {
                        float w = wk[ci * 9 + dy * 3 + dx];
                        a0 = fmaf(w, patch[ci][dy][dx],     a0);
                        a1 = fmaf(w, patch[ci][dy][dx + 1], a1);
                        a2 = fmaf(w, patch[ci][dy + 1][dx], a2);
                        a3 = fmaf(w, patch[ci][dy + 1][dx + 1], a3);
                    }
            float m = fmaxf(fmaxf(a0, a1), fmaxf(a2, a3));
            if (j == 0) res.x = m; else if (j == 1) res.y = m;
            else if (j == 2) res.z = m; else res.w = m;
        }
        *(float4*)(obase + co0) = res;
    }
}

// ---- BN stats stage 1: NHWC data -> partials[b][C][2] (sum, sumsq) --------
template <int C>
__global__ __launch_bounds__(256)
void bn_partial_kernel(const float* __restrict__ data, int total,
                       float* __restrict__ partials)
{
    const int b = blockIdx.x, t = threadIdx.x;
    float s = 0.f, s2 = 0.f;
    for (int i = b * 256 + t; i < total; i += 256 * 256) {
        float v = data[i];
        s += v; s2 += v * v;
    }
    __shared__ float rs[256], rs2[256];
    rs[t] = s; rs2[t] = s2;
    __syncthreads();
    if (t < C) {
        #pragma unroll
        for (int off = C; off < 256; off += C) { s += rs[t + off]; s2 += rs2[t + off]; }
        partials[(b * C + t) * 2]     = s;
        partials[(b * C + t) * 2 + 1] = s2;
    }
}

// ---- BN stats stage 2: reduce partials -> a[c], c[c] ----------------------
__global__ __launch_bounds__(128)
void bn_finalize_kernel(const float* __restrict__ partials, int C, float cnt,
                        const float* __restrict__ g, const float* __restrict__ bb,
                        float* __restrict__ a_out, float* __restrict__ c_out)
{
    int t = threadIdx.x;
    if (t >= C) return;
    float s = 0.f, s2 = 0.f;
    for (int i = 0; i < 256; ++i) {
        s  += partials[(i * C + t) * 2];
        s2 += partials[(i * C + t) * 2 + 1];
    }
    float mean = s / cnt;
    float var  = s2 / cnt - mean * mean;
    float a = g[t] * rsqrtf(var + 1e-5f);
    a_out[t] = a;
    c_out[t] = bb[t] - mean * a;
}

// ---- MFMA conv(CIN->128, 3x3 pad1) on bn-relu'd-on-the-fly input + pool ---
// in: NHWC f32 raw (32,WIN,WIN,CIN); bn applied during staging.
// Block: 16x16 pixel tile x 64 co. Wave: 4 M-frags x 4 N-frags.
template <int CIN, int WIN>
__global__ __launch_bounds__(256, 3)
void conv_mfma_kernel(const float* __restrict__ in, const float* __restrict__ bna,
                      const float* __restrict__ bnc, const short* __restrict__ Wth,
                      const short* __restrict__ Wtl, const float* __restrict__ Bias,
                      float* __restrict__ out)
{
    constexpr int CC    = CIN / 32;
    constexpr int POW   = WIN / 2;
    constexpr int TILES = WIN / 16;
    const int bx  = blockIdx.x;
    const int coh = blockIdx.y;            // co half (64 each)
    const int n   = blockIdx.z;
    const int ty = bx / TILES, tx = bx % TILES;
    const int y0 = ty * 16, x0 = tx * 16;
    const int tid  = threadIdx.x;
    const int w    = tid >> 6;
    const int lane = tid & 63;
    const int lrow = lane & 15;            // A row / B col / D col
    const int seg  = lane >> 4;            // 8-ci k segment

    // A tiles: [hi/lo][seg][halo point(18x18)][8 ci] bf16 = 41472 B
    __shared__ __align__(16) short sA[2][4][324][8];

    f32x4 acc[4][4];
    #pragma unroll
    for (int mf = 0; mf < 4; ++mf)
        #pragma unroll
        for (int nf = 0; nf < 4; ++nf) acc[mf][nf] = (f32x4){0.f, 0.f, 0.f, 0.f};

    #pragma unroll 1
    for (int c = 0; c < CC; ++c) {
        // ---- stage chunk c: bn+relu+f32->bf16(hi,lo), seg-major layout ----
        #pragma unroll
        for (int rep = 0; rep < 6; ++rep) {
            int u = tid + rep * 256;
            if (u < 1296) {
                int slot = u / 324, p = u - slot * 324;
                int hy = p / 18, hx = p - hy * 18;
                int y = y0 - 1 + hy, x = x0 - 1 + hx;
                int cb = c * 32 + slot * 8;
                float4 f0 = make_float4(0.f, 0.f, 0.f, 0.f);
                float4 f1 = make_float4(0.f, 0.f, 0.f, 0.f);
                if ((unsigned)y < (unsigned)WIN && (unsigned)x < (unsigned)WIN) {
                    const float* s = in + (size_t)((n * WIN + y) * WIN + x) * CIN + cb;
                    f0 = *(const float4*)s;
                    f1 = *(const float4*)(s + 4);
                }
                float4 a0 = *(const float4*)(bna + cb);
                float4 a1 = *(const float4*)(bna + cb + 4);
                float4 c0 = *(const float4*)(bnc + cb);
                float4 c1 = *(const float4*)(bnc + cb + 4);
                float e[8] = {
                    fmaxf(fmaf(f0.x, a0.x, c0.x), 0.f),
                    fmaxf(fmaf(f0.y, a0.y, c0.y), 0.f),
                    fmaxf(fmaf(f0.z, a0.z, c0.z), 0.f),
                    fmaxf(fmaf(f0.w, a0.w, c0.w), 0.f),
                    fmaxf(fmaf(f1.x, a1.x, c1.x), 0.f),
                    fmaxf(fmaf(f1.y, a1.y, c1.y), 0.f),
                    fmaxf(fmaf(f1.z, a1.z, c1.z), 0.f),
                    fmaxf(fmaf(f1.w, a1.w, c1.w), 0.f)};
                unsigned hpk[4], lpk[4];
                #pragma unroll
                for (int q = 0; q < 4; ++q) {
                    unsigned short h0 = f2bf(e[2 * q]), h1 = f2bf(e[2 * q + 1]);
                    unsigned short l0 = f2bf(e[2 * q] - bfhi(h0));
                    unsigned short l1 = f2bf(e[2 * q + 1] - bfhi(h1));
                    hpk[q] = (unsigned)h0 | ((unsigned)h1 << 16);
                    lpk[q] = (unsigned)l0 | ((unsigned)l1 << 16);
                }
                *(int4*)&sA[0][slot][p][0] =
                    make_int4((int)hpk[0], (int)hpk[1], (int)hpk[2], (int)hpk[3]);
                *(int4*)&sA[1][slot][p][0] =
                    make_int4((int)lpk[0], (int)lpk[1], (int)lpk[2], (int)lpk[3]);
            }
        }
        __syncthreads();

        // ---- compute: 9 taps x (8 A ds_reads + 8 B loads -> 48 MFMAs) -----
        const short* baseH = &sA[0][0][0][0];
        const short* baseL = &sA[1][0][0][0];
        #pragma unroll 3
        for (int tap = 0; tap < 9; ++tap) {
            const int dy = tap / 3, dx = tap % 3;
            bf16x8 ah[4], al[4];
            #pragma unroll
            for (int mf = 0; mf < 4; ++mf) {
                int idx = seg * 324 + (w * 4 + mf + dy) * 18 + (lrow + dx);
                ah[mf] = *(const bf16x8*)(baseH + idx * 8);
                al[mf] = *(const bf16x8*)(baseL + idx * 8);
            }
            #pragma unroll
            for (int nf = 0; nf < 4; ++nf) {
                int co = coh * 64 + nf * 16 + lrow;
                const short* wp = Wth + ((size_t)(co * 9 + tap)) * CIN + c * 32 + seg * 8;
                const short* wq = Wtl + ((size_t)(co * 9 + tap)) * CIN + c * 32 + seg * 8;
                bf16x8 bh = *(const bf16x8*)wp;
                bf16x8 bl = *(const bf16x8*)wq;
                #pragma unroll
                for (int mf = 0; mf < 4; ++mf) {
                    acc[mf][nf] = __builtin_amdgcn_mfma_f32_16x16x32_bf16(
                        ah[mf], bh, acc[mf][nf], 0, 0, 0);
                    acc[mf][nf] = __builtin_amdgcn_mfma_f32_16x16x32_bf16(
                        al[mf], bh, acc[mf][nf], 0, 0, 0);
                    acc[mf][nf] = __builtin_amdgcn_mfma_f32_16x16x32_bf16(
                        ah[mf], bl, acc[mf][nf], 0, 0, 0);
                }
            }
        }
        __syncthreads();       // protect sA before next chunk's staging
    }

    // ---- epilogue: h-pool in regs, v-pool across mf pair, +bias, NHWC -----
    // D frag: col(co)=lrow, pre-pool x = 4*seg + reg, y = y0 + w*4 + mf.
    #pragma unroll
    for (int mf = 0; mf < 4; mf += 2) {
        const int ypo = (y0 >> 1) + w * 2 + (mf >> 1);
        const int xp0 = (x0 >> 1) + seg * 2;
        #pragma unroll
        for (int nf = 0; nf < 4; ++nf) {
            int co = coh * 64 + nf * 16 + lrow;
            float bv = Bias[co];
            f32x4 u = acc[mf][nf], v = acc[mf + 1][nf];
            float o0 = fmaxf(fmaxf(u[0], u[1]), fmaxf(v[0], v[1]));
            float o1 = fmaxf(fmaxf(u[2], u[3]), fmaxf(v[2], v[3]));
            float* ob = out + (size_t)((n * POW + ypo) * POW + xp0) * 128 + co;
            ob[0]   = o0 + bv;
            ob[128] = o1 + bv;
        }
    }
}

// ---------------- VIN head: one block per image (NHWC pool3) ---------------
__global__ __launch_bounds__(256)
void vin_kernel(const float* __restrict__ pool3, const float* __restrict__ bn_a,
                const float* __restrict__ bn_c, const float* __restrict__ r_w,
                const float* __restrict__ q_w, const float* __restrict__ w_vi,
                const float* __restrict__ crit_w, const float* __restrict__ crit_b,
                const int* __restrict__ Kp, float* __restrict__ out_critic,
                float* __restrict__ out_q)
{
    const int n = blockIdx.x;
    const int tid = threadIdx.x;
    const int px = tid & 15, py = tid >> 4;

    __shared__ float s_cr[16][256];
    __shared__ float s_v[20][20];
    __shared__ float s_qw[16][25];
    __shared__ float s_wvi[16][25];
    __shared__ float s_rw[128];
    __shared__ float s_red[256];

    for (int i = tid; i < 400; i += 256) {
        s_qw[i / 25][i % 25]  = q_w[i];
        s_wvi[i / 25][i % 25] = w_vi[i];
        s_v[i / 20][i % 20]   = 0.f;
    }
    if (tid < 128) s_rw[tid] = r_w[tid];
    __syncthreads();

    float r = 0.f;
    const float* p3 = pool3 + ((size_t)n * 256 + tid) * 128;
    #pragma unroll 1
    for (int ci0 = 0; ci0 < 128; ci0 += 4) {
        float4 v4 = *(const float4*)(p3 + ci0);
        float e[4] = {v4.x, v4.y, v4.z, v4.w};
        #pragma unroll
        for (int j = 0; j < 4; ++j) {
            float x = fmaxf(fmaf(e[j], bn_a[ci0 + j], bn_c[ci0 + j]), 0.f);
            r = fmaf(x, s_rw[ci0 + j], r);
        }
    }
    s_v[py + 2][px + 2] = r;
    __syncthreads();

    float cr[16];
    #pragma unroll
    for (int co = 0; co < 16; ++co) cr[co] = 0.f;
    #pragma unroll
    for (int dy = 0; dy < 5; ++dy)
        #pragma unroll
        for (int dx = 0; dx < 5; ++dx) {
            float rv = s_v[py + dy][px + dx];
            #pragma unroll
            for (int co = 0; co < 16; ++co)
                cr[co] = fmaf(s_qw[co][dy * 5 + dx], rv, cr[co]);
        }
    float v = cr[0];
    #pragma unroll
    for (int co = 0; co < 16; ++co) { s_cr[co][tid] = cr[co]; v = fmaxf(v, cr[co]); }
    __syncthreads();
    s_v[py + 2][px + 2] = v;
    __syncthreads();

    const int K = Kp[0];
    float q[16];
    #pragma unroll 1
    for (int it = 0; it < K; ++it) {
        #pragma unroll
        for (int co = 0; co < 16; ++co) q[co] = s_cr[co][tid];
        #pragma unroll
        for (int dy = 0; dy < 5; ++dy)
            #pragma unroll
            for (int dx = 0; dx < 5; ++dx) {
                float vv = s_v[py + dy][px + dx];
                #pragma unroll
                for (int co = 0; co < 16; ++co)
                    q[co] = fmaf(s_wvi[co][dy * 5 + dx], vv, q[co]);
            }
        float nv = q[0];
        #pragma unroll
        for (int co = 1; co < 16; ++co) nv = fmaxf(nv, q[co]);
        __syncthreads();
        s_v[py + 2][px + 2] = nv;
        __syncthreads();
        v = nv;
    }

    #pragma unroll
    for (int co = 0; co < 16; ++co)
        out_q[(size_t)n * 4096 + co * 256 + tid] = q[co];

    s_red[tid] = v * crit_w[tid];
    __syncthreads();
    for (int off = 128; off > 0; off >>= 1) {
        if (tid < off) s_red[tid] += s_red[tid + off];
        __syncthreads();
    }
    if (tid == 0) out_critic[n] = s_red[0] + crit_b[0];
}

// ---------------------------------------------------------------------------
extern "C" void kernel_launch(void* const* d_in, const int* in_sizes, int n_in,
                              void* d_out, int out_size, void* d_ws, size_t ws_size,
                              hipStream_t stream)
{
    const float* X      = (const float*)d_in[0];
    // d_in[1] = obs (unused)
    const float* h1_w   = (const float*)d_in[2];
    const float* h1_b   = (const float*)d_in[3];
    const float* bn1_g  = (const float*)d_in[4];
    const float* bn1_b  = (const float*)d_in[5];
    const float* h2_w   = (const float*)d_in[6];
    const float* h2_b   = (const float*)d_in[7];
    const float* bn2_g  = (const float*)d_in[8];
    const float* bn2_b  = (const float*)d_in[9];
    const float* h3_w   = (const float*)d_in[10];
    const float* h3_b   = (const float*)d_in[11];
    const float* bn3_g  = (const float*)d_in[12];
    const float* bn3_b  = (const float*)d_in[13];
    const float* r_w    = (const float*)d_in[14];
    const float* q_w    = (const float*)d_in[15];
    const float* w_vi   = (const float*)d_in[16];
    const float* crit_w = (const float*)d_in[17];
    const float* crit_b = (const float*)d_in[18];
    const int*   Kp     = (const int*)d_in[19];

    // workspace (floats); high-water 12,870,656 fl = 51.5 MB (< 54.5 proven)
    float* ws    = (float*)d_ws;
    short* W2H   = (short*)(ws);            // 73728 shorts
    short* W2L   = (short*)(ws + 36864);
    short* W3H   = (short*)(ws + 73728);    // 147456 shorts
    short* W3L   = (short*)(ws + 147456);
    float* part  = ws + 221184;             // 256*128*2 = 65536 fl
    float* prm   = ws + 286720;             // bn params (1024 fl)
    float* a1 = prm, *c1 = prm + 64, *a2 = prm + 128, *c2 = prm + 256,
         * a3 = prm + 384, *c3 = prm + 512;
    float* buf1  = ws + 287744;             // 32*64*64*64  NHWC raw conv1+pool
    float* buf2  = ws + 8676352;            // 32*32*32*128 NHWC raw conv2+pool
    float* pool3 = ws + 287744;             // 32*16*16*128 (aliases buf1)

    float* out_critic = (float*)d_out;      // 32
    float* out_q      = out_critic + 32;    // 32*4096

    wt_kernel<64><<<(128 * 64 * 9 + 255) / 256, 256, 0, stream>>>(h2_w, W2H, W2L);
    wt_kernel<128><<<(128 * 128 * 9 + 255) / 256, 256, 0, stream>>>(h3_w, W3H, W3L);

    conv1_pool_kernel<<<dim3(16, 32), 256, 0, stream>>>(X, h1_w, h1_b, buf1);

    bn_partial_kernel<64><<<256, 256, 0, stream>>>(buf1, 8388608, part);
    bn_finalize_kernel<<<1, 128, 0, stream>>>(part, 64, 131072.f, bn1_g, bn1_b, a1, c1);

    conv_mfma_kernel<64, 64><<<dim3(16, 2, 32), 256, 0, stream>>>(
        buf1, a1, c1, W2H, W2L, h2_b, buf2);

    bn_partial_kernel<128><<<256, 256, 0, stream>>>(buf2, 4194304, part);
    bn_finalize_kernel<<<1, 128, 0, stream>>>(part, 128, 32768.f, bn2_g, bn2_b, a2, c2);

    conv_mfma_kernel<128, 32><<<dim3(4, 2, 32), 256, 0, stream>>>(
        buf2, a2, c2, W3H, W3L, h3_b, pool3);

    bn_partial_kernel<128><<<256, 256, 0, stream>>>(pool3, 1048576, part);
    bn_finalize_kernel<<<1, 128, 0, stream>>>(part, 128, 8192.f, bn3_g, bn3_b, a3, c3);

    vin_kernel<<<32, 256, 0, stream>>>(pool3, a3, c3, r_w, q_w, w_vi,
                                       crit_w, crit_b, Kp, out_critic, out_q);
}

// Round 12
// 431.398 us; speedup vs baseline: 3.3371x; 1.1755x over previous
//
#include <hip/hip_runtime.h>
#include <hip/hip_bf16.h>

// ---------------------------------------------------------------------------
// VIN forward (r12): MFMA implicit GEMM, coalesced B + pipelined A staging.
// History: r10 777us (MfmaUtil 8.5%, starved) -> r11 507us (conv2 114us,
//   MfmaUtil 20%, VALU 14% -> latency-bound: scattered B loads (64 lines per
//   wave load) + exposed A-staging latency; conv3 at 1 block/CU).
// r12: (1) weight layout [tap][cchunk][cb16][seg][lrow][8ci] -> B-fragment
//   load = base + lane*16B, fully coalesced (1KB/wave-load).
//   (2) T14 async-stage: issue chunk c+1 A-loads to regs (static idx), MFMA
//   chunk c, barrier, convert+ds_write, barrier. bn params in LDS.
//   (3) conv3 NF=2 (co quarters) -> 512 blocks = 2/CU.
//   (4) launch_bounds(256,2): no spill risk (LDS caps at 3 blocks anyway).
// ---------------------------------------------------------------------------

using bf16x8 = __attribute__((ext_vector_type(8))) short;
using f32x4  = __attribute__((ext_vector_type(4))) float;

__device__ __forceinline__ unsigned short f2bf(float x) {
    union { float f; unsigned u; } v; v.f = x;
    unsigned r = (v.u + 0x7FFFu + ((v.u >> 16) & 1u)) >> 16;
    return (unsigned short)r;
}
__device__ __forceinline__ float bfhi(unsigned short h) {
    union { unsigned u; float f; } v; v.u = ((unsigned)h) << 16;
    return v.f;
}

// ---- weight transform: OIHW f32 -> [tap][c][cb][seg][lrow][8] bf16 hi/lo --
template <int CIN>
__global__ __launch_bounds__(256)
void wt_kernel(const float* __restrict__ W, short* __restrict__ Wh,
               short* __restrict__ Wl)
{
    constexpr int CC = CIN / 32;
    constexpr int TOTAL = 128 * CIN * 9;
    int i = blockIdx.x * 256 + threadIdx.x;
    if (i >= TOTAL) return;
    int ci = i % CIN;
    int j  = i / CIN;
    int tap = j % 9, co = j / 9;
    float x = W[(co * CIN + ci) * 9 + tap];
    int c = ci >> 5, seg = (ci >> 3) & 3, e = ci & 7;
    int cb = co >> 4, lr = co & 15;
    size_t oi = ((((size_t)(tap * CC + c) * 8 + cb) * 4 + seg) * 16 + lr) * 8 + e;
    unsigned short h = f2bf(x);
    Wh[oi] = (short)h;
    Wl[oi] = (short)f2bf(x - bfhi(h));
}

// ------- conv1: X(32,3,128,128) -> pool1 NHWC f32 (32,64,64,64ci) ----------
__global__ __launch_bounds__(256)
void conv1_pool_kernel(const float* __restrict__ X, const float* __restrict__ W,
                       const float* __restrict__ Bias, float* __restrict__ out)
{
    const int sp  = blockIdx.x;
    const int n   = blockIdx.y;
    const int ty0 = (sp >> 2) * 16;
    const int tx0 = (sp & 3) * 16;
    const int tid = threadIdx.x;
    const int px = tid & 15, py = tid >> 4;

    __shared__ float s_in[3][34][34];

    const int gy0 = 2 * ty0 - 1, gx0 = 2 * tx0 - 1;
    for (int idx = tid; idx < 3 * 1156; idx += 256) {
        int ci = idx / 1156, rem = idx - ci * 1156;
        int ly = rem / 34, lx = rem - ly * 34;
        int gy = gy0 + ly, gx = gx0 + lx;
        float v = 0.f;
        if ((unsigned)gy < 128u && (unsigned)gx < 128u)
            v = X[((n * 3 + ci) << 14) + (gy << 7) + gx];
        s_in[ci][ly][lx] = v;
    }
    __syncthreads();

    float patch[3][4][4];
    #pragma unroll
    for (int ci = 0; ci < 3; ++ci)
        #pragma unroll
        for (int r = 0; r < 4; ++r) {
            float2 a = *(const float2*)&s_in[ci][2 * py + r][2 * px];
            float2 b = *(const float2*)&s_in[ci][2 * py + r][2 * px + 2];
            patch[ci][r][0] = a.x; patch[ci][r][1] = a.y;
            patch[ci][r][2] = b.x; patch[ci][r][3] = b.y;
        }

    float* obase = out + (((size_t)(n * 64 + ty0 + py) * 64) + tx0 + px) * 64;
    #pragma unroll 1
    for (int co0 = 0; co0 < 64; co0 += 4) {
        float4 res;
        #pragma unroll
        for (int j = 0; j < 4; ++j) {
            int co = co0 + j;
            float wk[27];                // wave-uniform -> s_load
            const float* wp = W + co * 27;
            #pragma unroll
            for (int k = 0; k < 27; ++k) wk[k] = wp[k];
            float b0 = Bias[co];
            float a0 = b0, a1 = b0, a2 = b0, a3 = b0;
            #pragma unroll
            for (int ci = 0; ci < 3; ++ci)
                #pragma unroll
                for (int dy = 0; dy < 3; ++dy)
                    #pragma unroll
                    for (int dx = 0; dx < 3; ++dx) {
                        float w = wk[ci * 9 + dy * 3 + dx];
                        a0 = fmaf(w, patch[ci][dy][dx],     a0);
                        a1 = fmaf(w, patch[ci][dy][dx + 1], a1);
                        a2 = fmaf(w, patch[ci][dy + 1][dx], a2);
                        a3 = fmaf(w, patch[ci][dy + 1][dx + 1], a3);
                    }
            float m = fmaxf(fmaxf(a0, a1), fmaxf(a2, a3));
            if (j == 0) res.x = m; else if (j == 1) res.y = m;
            else if (j == 2) res.z = m; else res.w = m;
        }
        *(float4*)(obase + co0) = res;
    }
}

// ---- BN stats stage 1: NHWC data -> partials[b][C][2] (sum, sumsq) --------
template <int C>
__global__ __launch_bounds__(256)
void bn_partial_kernel(const float* __restrict__ data, int total,
                       float* __restrict__ partials)
{
    const int b = blockIdx.x, t = threadIdx.x;
    float s = 0.f, s2 = 0.f;
    for (int i = b * 256 + t; i < total; i += 256 * 256) {
        float v = data[i];
        s += v; s2 += v * v;
    }
    __shared__ float rs[256], rs2[256];
    rs[t] = s; rs2[t] = s2;
    __syncthreads();
    if (t < C) {
        #pragma unroll
        for (int off = C; off < 256; off += C) { s += rs[t + off]; s2 += rs2[t + off]; }
        partials[(b * C + t) * 2]     = s;
        partials[(b * C + t) * 2 + 1] = s2;
    }
}

// ---- BN stats stage 2: reduce partials -> a[c], c[c] ----------------------
__global__ __launch_bounds__(128)
void bn_finalize_kernel(const float* __restrict__ partials, int C, float cnt,
                        const float* __restrict__ g, const float* __restrict__ bb,
                        float* __restrict__ a_out, float* __restrict__ c_out)
{
    int t = threadIdx.x;
    if (t >= C) return;
    float s = 0.f, s2 = 0.f;
    for (int i = 0; i < 256; ++i) {
        s  += partials[(i * C + t) * 2];
        s2 += partials[(i * C + t) * 2 + 1];
    }
    float mean = s / cnt;
    float var  = s2 / cnt - mean * mean;
    float a = g[t] * rsqrtf(var + 1e-5f);
    a_out[t] = a;
    c_out[t] = bb[t] - mean * a;
}

// ---- MFMA conv(CIN->128co-slice, 3x3 pad1) + pool, pipelined --------------
// Block: 16x16 px tile x NF*16 co. Wave: 4 M-frags x NF N-frags.
template <int CIN, int WIN, int NF>
__global__ __launch_bounds__(256, 2)
void conv_mfma_kernel(const float* __restrict__ in, const float* __restrict__ bna,
                      const float* __restrict__ bnc, const short* __restrict__ Wth,
                      const short* __restrict__ Wtl, const float* __restrict__ Bias,
                      float* __restrict__ out)
{
    constexpr int CC    = CIN / 32;
    constexpr int POW   = WIN / 2;
    constexpr int TILES = WIN / 16;
    const int bx  = blockIdx.x;
    const int coh = blockIdx.y;
    const int n   = blockIdx.z;
    const int ty = bx / TILES, tx = bx % TILES;
    const int y0 = ty * 16, x0 = tx * 16;
    const int tid  = threadIdx.x;
    const int wv   = tid >> 6;
    const int lane = tid & 63;
    const int lrow = lane & 15;
    const int seg  = lane >> 4;
    const int cbase = coh * NF;

    // A tile: hi plane [4 slot][324 pt][8ci] then lo plane; + bn params
    __shared__ __align__(16) short sAs[2 * 4 * 324 * 8];   // 41472 B
    __shared__ float sBnA[128], sBnC[128];

    if (tid < CIN) { sBnA[tid] = bna[tid]; sBnC[tid] = bnc[tid]; }

    // per-thread staging constants (all statically indexed -> registers)
    int offs[6], lds16[6], cia[6];
    unsigned vmask = 0;
    #pragma unroll
    for (int rep = 0; rep < 6; ++rep) {
        int u = tid + rep * 256;
        int slot = u / 324, p = u - slot * 324;
        int hy = p / 18, hx = p - hy * 18;
        int y = y0 - 1 + hy, x = x0 - 1 + hx;
        bool act = (u < 1296);
        bool val = act && ((unsigned)y < (unsigned)WIN) && ((unsigned)x < (unsigned)WIN);
        offs[rep]  = ((n * WIN + y) * WIN + x) * CIN + slot * 8;
        lds16[rep] = slot * 324 + p;
        cia[rep]   = slot * 8;
        if (val) vmask |= 1u << rep;
    }

    float4 pa[6], pb[6];

#define ISSUE_LOADS(cc) \
    _Pragma("unroll") \
    for (int rep = 0; rep < 6; ++rep) { \
        float4 z; z.x = 0.f; z.y = 0.f; z.z = 0.f; z.w = 0.f; \
        pa[rep] = z; pb[rep] = z; \
        if ((vmask >> rep) & 1u) { \
            const float* s_ = in + offs[rep] + (cc) * 32; \
            pa[rep] = *(const float4*)s_; \
            pb[rep] = *(const float4*)(s_ + 4); \
        } \
    }

#define CONVERT_WRITE(cc) \
    _Pragma("unroll") \
    for (int rep = 0; rep < 6; ++rep) { \
        if (rep < 5 || tid < 16) { \
            const float* ba_ = sBnA + (cc) * 32 + cia[rep]; \
            const float* bc_ = sBnC + (cc) * 32 + cia[rep]; \
            float4 a0_ = *(const float4*)ba_, a1_ = *(const float4*)(ba_ + 4); \
            float4 c0_ = *(const float4*)bc_, c1_ = *(const float4*)(bc_ + 4); \
            float e_[8] = { \
                fmaxf(fmaf(pa[rep].x, a0_.x, c0_.x), 0.f), \
                fmaxf(fmaf(pa[rep].y, a0_.y, c0_.y), 0.f), \
                fmaxf(fmaf(pa[rep].z, a0_.z, c0_.z), 0.f), \
                fmaxf(fmaf(pa[rep].w, a0_.w, c0_.w), 0.f), \
                fmaxf(fmaf(pb[rep].x, a1_.x, c1_.x), 0.f), \
                fmaxf(fmaf(pb[rep].y, a1_.y, c1_.y), 0.f), \
                fmaxf(fmaf(pb[rep].z, a1_.z, c1_.z), 0.f), \
                fmaxf(fmaf(pb[rep].w, a1_.w, c1_.w), 0.f)}; \
            unsigned hpk_[4], lpk_[4]; \
            _Pragma("unroll") \
            for (int q = 0; q < 4; ++q) { \
                unsigned short h0_ = f2bf(e_[2 * q]), h1_ = f2bf(e_[2 * q + 1]); \
                unsigned short l0_ = f2bf(e_[2 * q] - bfhi(h0_)); \
                unsigned short l1_ = f2bf(e_[2 * q + 1] - bfhi(h1_)); \
                hpk_[q] = (unsigned)h0_ | ((unsigned)h1_ << 16); \
                lpk_[q] = (unsigned)l0_ | ((unsigned)l1_ << 16); \
            } \
            *(int4*)&sAs[lds16[rep] * 8] = \
                make_int4((int)hpk_[0], (int)hpk_[1], (int)hpk_[2], (int)hpk_[3]); \
            *(int4*)&sAs[10368 + lds16[rep] * 8] = \
                make_int4((int)lpk_[0], (int)lpk_[1], (int)lpk_[2], (int)lpk_[3]); \
        } \
    }

#define COMPUTE(cc) \
    { const short* baseH_ = sAs; const short* baseL_ = sAs + 10368; \
      _Pragma("unroll 3") \
      for (int tap = 0; tap < 9; ++tap) { \
          const int dy_ = tap / 3, dx_ = tap % 3; \
          bf16x8 ah_[4], al_[4]; \
          _Pragma("unroll") \
          for (int mf = 0; mf < 4; ++mf) { \
              int idx_ = seg * 324 + (wv * 4 + mf + dy_) * 18 + (lrow + dx_); \
              ah_[mf] = *(const bf16x8*)(baseH_ + idx_ * 8); \
              al_[mf] = *(const bf16x8*)(baseL_ + idx_ * 8); \
          } \
          _Pragma("unroll") \
          for (int nf = 0; nf < NF; ++nf) { \
              size_t wo_ = ((((size_t)(tap * CC + (cc)) * 8 + cbase + nf) * 4 + seg) * 16 + lrow) * 8; \
              bf16x8 bh_ = *(const bf16x8*)(Wth + wo_); \
              bf16x8 bl_ = *(const bf16x8*)(Wtl + wo_); \
              _Pragma("unroll") \
              for (int mf = 0; mf < 4; ++mf) { \
                  acc[mf][nf] = __builtin_amdgcn_mfma_f32_16x16x32_bf16(ah_[mf], bh_, acc[mf][nf], 0, 0, 0); \
                  acc[mf][nf] = __builtin_amdgcn_mfma_f32_16x16x32_bf16(al_[mf], bh_, acc[mf][nf], 0, 0, 0); \
                  acc[mf][nf] = __builtin_amdgcn_mfma_f32_16x16x32_bf16(ah_[mf], bl_, acc[mf][nf], 0, 0, 0); \
              } \
          } \
      } }

    f32x4 acc[4][NF];
    #pragma unroll
    for (int mf = 0; mf < 4; ++mf)
        #pragma unroll
        for (int nf = 0; nf < NF; ++nf) acc[mf][nf] = (f32x4){0.f, 0.f, 0.f, 0.f};

    ISSUE_LOADS(0)
    __syncthreads();                 // sBn ready (also covers nothing else)
    CONVERT_WRITE(0)
    __syncthreads();                 // sA chunk 0 ready

    #pragma unroll 1
    for (int c = 0; c < CC; ++c) {
        if (c + 1 < CC) ISSUE_LOADS(c + 1)        // in flight under MFMAs
        COMPUTE(c)
        __syncthreads();             // all reads of sA done
        if (c + 1 < CC) {
            CONVERT_WRITE(c + 1)     // vmcnt wait lands here, post-compute
            __syncthreads();         // sA chunk c+1 ready
        }
    }

#undef ISSUE_LOADS
#undef CONVERT_WRITE
#undef COMPUTE

    // epilogue: h-pool in regs, v-pool across mf pair, +bias, NHWC store
    #pragma unroll
    for (int mf = 0; mf < 4; mf += 2) {
        const int ypo = (y0 >> 1) + wv * 2 + (mf >> 1);
        const int xp0 = (x0 >> 1) + seg * 2;
        #pragma unroll
        for (int nf = 0; nf < NF; ++nf) {
            int co = (cbase + nf) * 16 + lrow;
            float bv = Bias[co];
            f32x4 u = acc[mf][nf], v = acc[mf + 1][nf];
            float o0 = fmaxf(fmaxf(u[0], u[1]), fmaxf(v[0], v[1]));
            float o1 = fmaxf(fmaxf(u[2], u[3]), fmaxf(v[2], v[3]));
            float* ob = out + (size_t)((n * POW + ypo) * POW + xp0) * 128 + co;
            ob[0]   = o0 + bv;
            ob[128] = o1 + bv;
        }
    }
}

// ---------------- VIN head: one block per image (NHWC pool3) ---------------
__global__ __launch_bounds__(256)
void vin_kernel(const float* __restrict__ pool3, const float* __restrict__ bn_a,
                const float* __restrict__ bn_c, const float* __restrict__ r_w,
                const float* __restrict__ q_w, const float* __restrict__ w_vi,
                const float* __restrict__ crit_w, const float* __restrict__ crit_b,
                const int* __restrict__ Kp, float* __restrict__ out_critic,
                float* __restrict__ out_q)
{
    const int n = blockIdx.x;
    const int tid = threadIdx.x;
    const int px = tid & 15, py = tid >> 4;

    __shared__ float s_cr[16][256];
    __shared__ float s_v[20][20];
    __shared__ float s_qw[16][25];
    __shared__ float s_wvi[16][25];
    __shared__ float s_rw[128];
    __shared__ float s_red[256];

    for (int i = tid; i < 400; i += 256) {
        s_qw[i / 25][i % 25]  = q_w[i];
        s_wvi[i / 25][i % 25] = w_vi[i];
        s_v[i / 20][i % 20]   = 0.f;
    }
    if (tid < 128) s_rw[tid] = r_w[tid];
    __syncthreads();

    float r = 0.f;
    const float* p3 = pool3 + ((size_t)n * 256 + tid) * 128;
    #pragma unroll 1
    for (int ci0 = 0; ci0 < 128; ci0 += 4) {
        float4 v4 = *(const float4*)(p3 + ci0);
        float e[4] = {v4.x, v4.y, v4.z, v4.w};
        #pragma unroll
        for (int j = 0; j < 4; ++j) {
            float x = fmaxf(fmaf(e[j], bn_a[ci0 + j], bn_c[ci0 + j]), 0.f);
            r = fmaf(x, s_rw[ci0 + j], r);
        }
    }
    s_v[py + 2][px + 2] = r;
    __syncthreads();

    float cr[16];
    #pragma unroll
    for (int co = 0; co < 16; ++co) cr[co] = 0.f;
    #pragma unroll
    for (int dy = 0; dy < 5; ++dy)
        #pragma unroll
        for (int dx = 0; dx < 5; ++dx) {
            float rv = s_v[py + dy][px + dx];
            #pragma unroll
            for (int co = 0; co < 16; ++co)
                cr[co] = fmaf(s_qw[co][dy * 5 + dx], rv, cr[co]);
        }
    float v = cr[0];
    #pragma unroll
    for (int co = 0; co < 16; ++co) { s_cr[co][tid] = cr[co]; v = fmaxf(v, cr[co]); }
    __syncthreads();
    s_v[py + 2][px + 2] = v;
    __syncthreads();

    const int K = Kp[0];
    float q[16];
    #pragma unroll 1
    for (int it = 0; it < K; ++it) {
        #pragma unroll
        for (int co = 0; co < 16; ++co) q[co] = s_cr[co][tid];
        #pragma unroll
        for (int dy = 0; dy < 5; ++dy)
            #pragma unroll
            for (int dx = 0; dx < 5; ++dx) {
                float vv = s_v[py + dy][px + dx];
                #pragma unroll
                for (int co = 0; co < 16; ++co)
                    q[co] = fmaf(s_wvi[co][dy * 5 + dx], vv, q[co]);
            }
        float nv = q[0];
        #pragma unroll
        for (int co = 1; co < 16; ++co) nv = fmaxf(nv, q[co]);
        __syncthreads();
        s_v[py + 2][px + 2] = nv;
        __syncthreads();
        v = nv;
    }

    #pragma unroll
    for (int co = 0; co < 16; ++co)
        out_q[(size_t)n * 4096 + co * 256 + tid] = q[co];

    s_red[tid] = v * crit_w[tid];
    __syncthreads();
    for (int off = 128; off > 0; off >>= 1) {
        if (tid < off) s_red[tid] += s_red[tid + off];
        __syncthreads();
    }
    if (tid == 0) out_critic[n] = s_red[0] + crit_b[0];
}

// ---------------------------------------------------------------------------
extern "C" void kernel_launch(void* const* d_in, const int* in_sizes, int n_in,
                              void* d_out, int out_size, void* d_ws, size_t ws_size,
                              hipStream_t stream)
{
    const float* X      = (const float*)d_in[0];
    // d_in[1] = obs (unused)
    const float* h1_w   = (const float*)d_in[2];
    const float* h1_b   = (const float*)d_in[3];
    const float* bn1_g  = (const float*)d_in[4];
    const float* bn1_b  = (const float*)d_in[5];
    const float* h2_w   = (const float*)d_in[6];
    const float* h2_b   = (const float*)d_in[7];
    const float* bn2_g  = (const float*)d_in[8];
    const float* bn2_b  = (const float*)d_in[9];
    const float* h3_w   = (const float*)d_in[10];
    const float* h3_b   = (const float*)d_in[11];
    const float* bn3_g  = (const float*)d_in[12];
    const float* bn3_b  = (const float*)d_in[13];
    const float* r_w    = (const float*)d_in[14];
    const float* q_w    = (const float*)d_in[15];
    const float* w_vi   = (const float*)d_in[16];
    const float* crit_w = (const float*)d_in[17];
    const float* crit_b = (const float*)d_in[18];
    const int*   Kp     = (const int*)d_in[19];

    // workspace (floats); high-water 12,870,656 fl = 51.5 MB (< 54.5 proven)
    float* ws    = (float*)d_ws;
    short* W2H   = (short*)(ws);            // 73728 shorts
    short* W2L   = (short*)(ws + 36864);
    short* W3H   = (short*)(ws + 73728);    // 147456 shorts
    short* W3L   = (short*)(ws + 147456);
    float* part  = ws + 221184;             // 256*128*2 = 65536 fl
    float* prm   = ws + 286720;             // bn params (1024 fl)
    float* a1 = prm, *c1 = prm + 64, *a2 = prm + 128, *c2 = prm + 256,
         * a3 = prm + 384, *c3 = prm + 512;
    float* buf1  = ws + 287744;             // 32*64*64*64  NHWC raw conv1+pool
    float* buf2  = ws + 8676352;            // 32*32*32*128 NHWC raw conv2+pool
    float* pool3 = ws + 287744;             // 32*16*16*128 (aliases buf1)

    float* out_critic = (float*)d_out;      // 32
    float* out_q      = out_critic + 32;    // 32*4096

    wt_kernel<64><<<(128 * 64 * 9 + 255) / 256, 256, 0, stream>>>(h2_w, W2H, W2L);
    wt_kernel<128><<<(128 * 128 * 9 + 255) / 256, 256, 0, stream>>>(h3_w, W3H, W3L);

    conv1_pool_kernel<<<dim3(16, 32), 256, 0, stream>>>(X, h1_w, h1_b, buf1);

    bn_partial_kernel<64><<<256, 256, 0, stream>>>(buf1, 8388608, part);
    bn_finalize_kernel<<<1, 128, 0, stream>>>(part, 64, 131072.f, bn1_g, bn1_b, a1, c1);

    conv_mfma_kernel<64, 64, 4><<<dim3(16, 2, 32), 256, 0, stream>>>(
        buf1, a1, c1, W2H, W2L, h2_b, buf2);

    bn_partial_kernel<128><<<256, 256, 0, stream>>>(buf2, 4194304, part);
    bn_finalize_kernel<<<1, 128, 0, stream>>>(part, 128, 32768.f, bn2_g, bn2_b, a2, c2);

    conv_mfma_kernel<128, 32, 2><<<dim3(4, 4, 32), 256, 0, stream>>>(
        buf2, a2, c2, W3H, W3L, h3_b, pool3);

    bn_partial_kernel<128><<<256, 256, 0, stream>>>(pool3, 1048576, part);
    bn_finalize_kernel<<<1, 128, 0, stream>>>(part, 128, 8192.f, bn3_g, bn3_b, a3, c3);

    vin_kernel<<<32, 256, 0, stream>>>(pool3, a3, c3, r_w, q_w, w_vi,
                                       crit_w, crit_b, Kp, out_critic, out_q);
}